// Round 3
// baseline (1082.093 us; speedup 1.0000x reference)
//
#include <hip/hip_runtime.h>
#include <hip/hip_fp16.h>
#include <math.h>

#define N_NODES   100000
#define N_EDGES   1250000
#define HID       64
#define N_RBF     32
#define N_GRAPHS  512
#define N_EXPERTS 8
#define N_LAYERS  3
#define CUTOFF    6.0f
#define GATE_IN   72
#define G1_DIM    64
#define G2_DIM    32
#define K_TAB     4096   // lerp intervals
#define NB_SCAN   391    // ceil(N_NODES/256)

// ---------------------------------------------------------------------------
// Filter table (fp32): f_i(w) = silu(rbf(w)@fW1^T+fb1)@fW2^T+fb2
// ---------------------------------------------------------------------------
__global__ __launch_bounds__(256) void build_tab(
    const float* __restrict__ fW1, const float* __restrict__ fb1,
    const float* __restrict__ fW2, const float* __restrict__ fb2,
    float* __restrict__ tab) {
  __shared__ float W1s[64][33];
  __shared__ float W2s[64][65];
  __shared__ float rbfs[4][32];
  __shared__ float h1s[4][64];
  int t = threadIdx.x;
  int wv = t >> 6, lane = t & 63;
  int layer = blockIdx.x / 1025;
  int k = (blockIdx.x % 1025) * 4 + wv;

  for (int i = t; i < 64 * 32; i += 256) W1s[i >> 5][i & 31] = fW1[layer * 2048 + i];
  for (int i = t; i < 64 * 64; i += 256) W2s[i >> 6][i & 63] = fW2[layer * 4096 + i];

  float w = (CUTOFF / (float)K_TAB) * (float)k;
  const float delta = CUTOFF / (float)(N_RBF - 1);
  const float coeff = -0.5f / (delta * delta);
  __syncthreads();

  if (lane < N_RBF) {
    float d = w - delta * (float)lane;
    rbfs[wv][lane] = expf(coeff * d * d);
  }
  __syncthreads();

  float s = fb1[layer * HID + lane];
#pragma unroll
  for (int j = 0; j < N_RBF; j++) s += rbfs[wv][j] * W1s[lane][j];
  h1s[wv][lane] = s / (1.0f + expf(-s));
  __syncthreads();

  float f = fb2[layer * HID + lane];
#pragma unroll
  for (int c = 0; c < HID; c++) f += h1s[wv][c] * W2s[lane][c];
  if (k <= K_TAB) tab[(layer * (K_TAB + 1) + k) * HID + lane] = f;
}

// Pack lerp pairs: tabP[layer][k][lane] = (tab[k], tab[k+1]) as half2
__global__ __launch_bounds__(256) void pack_tab(
    const float* __restrict__ tab, __half2* __restrict__ tabP) {
  int i = blockIdx.x * 256 + threadIdx.x;     // 3*4096*64
  if (i >= N_LAYERS * K_TAB * 64) return;
  int layer = i / (K_TAB * 64);
  int r = i - layer * (K_TAB * 64);
  const float* base = tab + layer * (K_TAB + 1) * 64;
  tabP[i] = __floats2half2_rn(base[r], base[r + 64]);
}

// ---------------------------------------------------------------------------
__global__ __launch_bounds__(256) void embed_kernel(
    const int* __restrict__ z, const float* __restrict__ emb,
    float* __restrict__ x) {
  int i = blockIdx.x * 256 + threadIdx.x;
  if (i < N_NODES * HID) {
    int n = i >> 6, h = i & 63;
    x[i] = emb[z[n] * HID + h];
  }
}

// ---------------------------------------------------------------------------
// CSR build
// ---------------------------------------------------------------------------
__global__ __launch_bounds__(256) void hist_kernel(
    const int* __restrict__ dst, int* __restrict__ deg) {
  int e = blockIdx.x * 256 + threadIdx.x;
  if (e < N_EDGES) atomicAdd(&deg[dst[e]], 1);
}

__global__ __launch_bounds__(256) void scan1_kernel(
    const int* __restrict__ deg, int* __restrict__ bsum) {
  __shared__ int sh[256];
  int t = threadIdx.x;
  int i = blockIdx.x * 256 + t;
  sh[t] = (i < N_NODES) ? deg[i] : 0;
  __syncthreads();
  for (int off = 128; off > 0; off >>= 1) {
    if (t < off) sh[t] += sh[t + off];
    __syncthreads();
  }
  if (t == 0) bsum[blockIdx.x] = sh[0];
}

__global__ __launch_bounds__(512) void scan2_kernel(int* __restrict__ bsum) {
  __shared__ int sh[512];
  int t = threadIdx.x;
  int v = (t < NB_SCAN) ? bsum[t] : 0;
  sh[t] = v;
  __syncthreads();
  for (int off = 1; off < 512; off <<= 1) {
    int add = (t >= off) ? sh[t - off] : 0;
    __syncthreads();
    sh[t] += add;
    __syncthreads();
  }
  if (t < NB_SCAN) bsum[t] = sh[t] - v;   // exclusive
}

__global__ __launch_bounds__(256) void scan3_kernel(
    const int* __restrict__ deg, const int* __restrict__ bsum,
    int* __restrict__ rowstart, int* __restrict__ cursor) {
  __shared__ int sh[256];
  int t = threadIdx.x;
  int i = blockIdx.x * 256 + t;
  int v = (i < N_NODES) ? deg[i] : 0;
  sh[t] = v;
  __syncthreads();
  for (int off = 1; off < 256; off <<= 1) {
    int add = (t >= off) ? sh[t - off] : 0;
    __syncthreads();
    sh[t] += add;
    __syncthreads();
  }
  if (i < N_NODES) {
    int rs = bsum[blockIdx.x] + sh[t] - v;
    rowstart[i] = rs;
    cursor[i] = rs;
  }
  if (i == 0) rowstart[N_NODES] = N_EDGES;
}

__global__ __launch_bounds__(256) void scatter_kernel(
    const int* __restrict__ src, const int* __restrict__ dst,
    const float* __restrict__ ew, int* __restrict__ cursor,
    unsigned* __restrict__ recs) {
  int e = blockIdx.x * 256 + threadIdx.x;
  if (e >= N_EDGES) return;
  int d = dst[e];
  int pos = atomicAdd(&cursor[d], 1);
  float uq = ew[e] * ((float)K_TAB * 8.0f / CUTOFF);
  int wq = (int)(uq + 0.5f);
  if (wq > 32767) wq = 32767;
  recs[pos] = ((unsigned)src[e] << 15) | (unsigned)wq;
}

// ---------------------------------------------------------------------------
// dense64: y[n][o] = (sum_c x[n][c]*W[o][c] + b[o]) -> fp16
// 4x4 register tile per thread: rows ty*4+i, cols tx+16*j (all LDS reads
// <=2-way bank aliasing = free).
// ---------------------------------------------------------------------------
__global__ __launch_bounds__(256) void dense64(
    const float* __restrict__ x, const float* __restrict__ W,
    const float* __restrict__ b, __half* __restrict__ y) {
  __shared__ float xs[64][68];
  __shared__ float Ws[64][68];
  int t = threadIdx.x;
  int row0 = blockIdx.x * 64;
  int tx = t & 15, ty = t >> 4;

  for (int i = t; i < 4096; i += 256) Ws[i >> 6][i & 63] = W[i];
  for (int i = t; i < 4096; i += 256) {
    int r = i >> 6, gr = row0 + r;
    xs[r][i & 63] = (gr < N_NODES) ? x[gr * 64 + (i & 63)] : 0.0f;
  }
  __syncthreads();

  float acc[4][4];
#pragma unroll
  for (int j = 0; j < 4; j++) {
    float bj = b[tx + 16 * j];
#pragma unroll
    for (int i = 0; i < 4; i++) acc[i][j] = bj;
  }
#pragma unroll
  for (int c4 = 0; c4 < 16; c4++) {
    float4 xv[4], wv[4];
#pragma unroll
    for (int i = 0; i < 4; i++) xv[i] = *(const float4*)&xs[ty * 4 + i][c4 * 4];
#pragma unroll
    for (int j = 0; j < 4; j++) wv[j] = *(const float4*)&Ws[tx + 16 * j][c4 * 4];
#pragma unroll
    for (int i = 0; i < 4; i++)
#pragma unroll
      for (int j = 0; j < 4; j++)
        acc[i][j] += xv[i].x * wv[j].x + xv[i].y * wv[j].y +
                     xv[i].z * wv[j].z + xv[i].w * wv[j].w;
  }
#pragma unroll
  for (int i = 0; i < 4; i++) {
    int gr = row0 + ty * 4 + i;
    if (gr < N_NODES)
#pragma unroll
      for (int j = 0; j < 4; j++)
        y[gr * 64 + tx + 16 * j] = __float2half(acc[i][j]);
  }
}

// ---------------------------------------------------------------------------
// update64: x[n] += silu(agg[n]@W1^T+b1)@W2^T+b2   (agg fp16 in)
// ---------------------------------------------------------------------------
__global__ __launch_bounds__(256) void update64(
    const __half* __restrict__ aggh,
    const float* __restrict__ W1, const float* __restrict__ b1,
    const float* __restrict__ W2, const float* __restrict__ b2,
    float* __restrict__ x) {
  __shared__ float as[64][68];
  __shared__ float Ws[64][68];
  int t = threadIdx.x;
  int row0 = blockIdx.x * 64;
  int tx = t & 15, ty = t >> 4;

  for (int i = t; i < 4096; i += 256) Ws[i >> 6][i & 63] = W1[i];
  for (int i = t; i < 2048; i += 256) {
    int r = i >> 5, c2 = (i & 31) * 2, gr = row0 + r;
    __half2 hv = __floats2half2_rn(0.0f, 0.0f);
    if (gr < N_NODES) hv = ((const __half2*)aggh)[gr * 32 + (i & 31)];
    as[r][c2]     = __low2float(hv);
    as[r][c2 + 1] = __high2float(hv);
  }
  __syncthreads();

  float acc[4][4];
#pragma unroll
  for (int j = 0; j < 4; j++) {
    float bj = b1[tx + 16 * j];
#pragma unroll
    for (int i = 0; i < 4; i++) acc[i][j] = bj;
  }
#pragma unroll
  for (int c4 = 0; c4 < 16; c4++) {
    float4 xv[4], wv[4];
#pragma unroll
    for (int i = 0; i < 4; i++) xv[i] = *(const float4*)&as[ty * 4 + i][c4 * 4];
#pragma unroll
    for (int j = 0; j < 4; j++) wv[j] = *(const float4*)&Ws[tx + 16 * j][c4 * 4];
#pragma unroll
    for (int i = 0; i < 4; i++)
#pragma unroll
      for (int j = 0; j < 4; j++)
        acc[i][j] += xv[i].x * wv[j].x + xv[i].y * wv[j].y +
                     xv[i].z * wv[j].z + xv[i].w * wv[j].w;
  }
  __syncthreads();   // all reads of as/Ws done
  // h = silu(acc) -> as; stage W2 -> Ws
#pragma unroll
  for (int i = 0; i < 4; i++)
#pragma unroll
    for (int j = 0; j < 4; j++) {
      float s = acc[i][j];
      as[ty * 4 + i][tx + 16 * j] = s / (1.0f + expf(-s));
    }
  for (int i = t; i < 4096; i += 256) Ws[i >> 6][i & 63] = W2[i];
  __syncthreads();

#pragma unroll
  for (int j = 0; j < 4; j++) {
    float bj = b2[tx + 16 * j];
#pragma unroll
    for (int i = 0; i < 4; i++) acc[i][j] = bj;
  }
#pragma unroll
  for (int c4 = 0; c4 < 16; c4++) {
    float4 xv[4], wv[4];
#pragma unroll
    for (int i = 0; i < 4; i++) xv[i] = *(const float4*)&as[ty * 4 + i][c4 * 4];
#pragma unroll
    for (int j = 0; j < 4; j++) wv[j] = *(const float4*)&Ws[tx + 16 * j][c4 * 4];
#pragma unroll
    for (int i = 0; i < 4; i++)
#pragma unroll
      for (int j = 0; j < 4; j++)
        acc[i][j] += xv[i].x * wv[j].x + xv[i].y * wv[j].y +
                     xv[i].z * wv[j].z + xv[i].w * wv[j].w;
  }
#pragma unroll
  for (int i = 0; i < 4; i++) {
    int gr = row0 + ty * 4 + i;
    if (gr < N_NODES)
#pragma unroll
      for (int j = 0; j < 4; j++)
        x[gr * 64 + tx + 16 * j] += acc[i][j];
  }
}

// ---------------------------------------------------------------------------
// CSR gather, fp16 payloads, half2-packed lerp table, 4-deep load pipeline.
// ---------------------------------------------------------------------------
__global__ __launch_bounds__(256) void gather_kernel(
    const int* __restrict__ rowstart, const unsigned* __restrict__ recs,
    const __half2* __restrict__ tabP, const __half* __restrict__ yh,
    __half* __restrict__ aggh) {
  int d = blockIdx.x * 4 + (threadIdx.x >> 6);
  int lane = threadIdx.x & 63;
  if (d >= N_NODES) return;
  int b0 = rowstart[d], b1 = rowstart[d + 1];
  float acc = 0.0f;
  int j = b0;
  for (; j + 4 <= b1; j += 4) {
    unsigned u0 = recs[j], u1 = recs[j + 1], u2 = recs[j + 2], u3 = recs[j + 3];
    float y0 = __half2float(yh[(u0 >> 15) * 64 + lane]);
    float y1 = __half2float(yh[(u1 >> 15) * 64 + lane]);
    float y2 = __half2float(yh[(u2 >> 15) * 64 + lane]);
    float y3 = __half2float(yh[(u3 >> 15) * 64 + lane]);
    __half2 p0 = tabP[((u0 & 32767u) >> 3) * 64 + lane];
    __half2 p1 = tabP[((u1 & 32767u) >> 3) * 64 + lane];
    __half2 p2 = tabP[((u2 & 32767u) >> 3) * 64 + lane];
    __half2 p3 = tabP[((u3 & 32767u) >> 3) * 64 + lane];
    float fr0 = (float)(u0 & 7u) * 0.125f;
    float fr1 = (float)(u1 & 7u) * 0.125f;
    float fr2 = (float)(u2 & 7u) * 0.125f;
    float fr3 = (float)(u3 & 7u) * 0.125f;
    float a0 = __low2float(p0), g0 = __high2float(p0);
    float a1 = __low2float(p1), g1 = __high2float(p1);
    float a2 = __low2float(p2), g2 = __high2float(p2);
    float a3 = __low2float(p3), g3 = __high2float(p3);
    acc += y0 * (a0 + (g0 - a0) * fr0);
    acc += y1 * (a1 + (g1 - a1) * fr1);
    acc += y2 * (a2 + (g2 - a2) * fr2);
    acc += y3 * (a3 + (g3 - a3) * fr3);
  }
  for (; j < b1; j++) {
    unsigned u = recs[j];
    float yv = __half2float(yh[(u >> 15) * 64 + lane]);
    __half2 p = tabP[((u & 32767u) >> 3) * 64 + lane];
    float fr = (float)(u & 7u) * 0.125f;
    float a = __low2float(p), g = __high2float(p);
    acc += yv * (a + (g - a) * fr);
  }
  aggh[d * 64 + lane] = __float2half(acc);
}

// ---------------------------------------------------------------------------
__global__ __launch_bounds__(256) void pool_kernel(
    const float* __restrict__ x, const int* __restrict__ batch,
    float* __restrict__ pooled, float* __restrict__ counts) {
  int wid = (blockIdx.x * 256 + threadIdx.x) >> 6;
  int lane = threadIdx.x & 63;
  int n0 = wid * 64;
  if (n0 >= N_NODES) return;
  int n1 = n0 + 64; if (n1 > N_NODES) n1 = N_NODES;
  int curg = batch[n0];
  float acc = 0.0f, cnt = 0.0f;
  for (int n = n0; n < n1; n++) {
    int g = batch[n];
    if (g != curg) {
      unsafeAtomicAdd(&pooled[curg * 64 + lane], acc);
      if (lane == 0) unsafeAtomicAdd(&counts[curg], cnt);
      curg = g; acc = 0.0f; cnt = 0.0f;
    }
    acc += x[n * 64 + lane];
    cnt += 1.0f;
  }
  unsafeAtomicAdd(&pooled[curg * 64 + lane], acc);
  if (lane == 0) unsafeAtomicAdd(&counts[curg], cnt);
}

// ---------------------------------------------------------------------------
__global__ __launch_bounds__(256) void gate_kernel(
    const float* __restrict__ pooled, const float* __restrict__ counts,
    const float* __restrict__ mlip,
    const float* __restrict__ gW1, const float* __restrict__ gb1,
    const float* __restrict__ gW2, const float* __restrict__ gb2,
    const float* __restrict__ gW3, const float* __restrict__ gb3,
    float* __restrict__ out) {
  __shared__ float ins[4][GATE_IN];
  __shared__ float h1s[4][G1_DIM];
  __shared__ float h2s[4][G2_DIM];
  __shared__ float lg[4][N_EXPERTS];
  int wv = threadIdx.x >> 6, lane = threadIdx.x & 63;
  int g = blockIdx.x * 4 + wv;

  float cnt = counts[g];
  if (cnt < 1.0f) cnt = 1.0f;
  ins[wv][lane] = pooled[g * 64 + lane] / cnt;
  if (lane < N_EXPERTS) ins[wv][64 + lane] = mlip[g * N_EXPERTS + lane];
  __syncthreads();

  {
    float s = gb1[lane];
    for (int c = 0; c < GATE_IN; c++) s += ins[wv][c] * gW1[lane * GATE_IN + c];
    h1s[wv][lane] = fmaxf(s, 0.0f);
  }
  __syncthreads();
  if (lane < G2_DIM) {
    float s = gb2[lane];
    for (int c = 0; c < G1_DIM; c++) s += h1s[wv][c] * gW2[lane * G1_DIM + c];
    h2s[wv][lane] = fmaxf(s, 0.0f);
  }
  __syncthreads();
  if (lane < N_EXPERTS) {
    float s = gb3[lane];
    for (int c = 0; c < G2_DIM; c++) s += h2s[wv][c] * gW3[lane * G2_DIM + c];
    lg[wv][lane] = s;
  }
  __syncthreads();
  if (lane < N_EXPERTS) {
    float m = -1e30f;
    for (int j = 0; j < N_EXPERTS; j++) m = fmaxf(m, lg[wv][j]);
    float den = 0.0f;
    for (int j = 0; j < N_EXPERTS; j++) den += expf(lg[wv][j] - m);
    float wgt = expf(lg[wv][lane] - m) / den;
    out[g * 8 + lane] = lg[wv][lane];
    out[N_GRAPHS * 8 + g * 8 + lane] = wgt;
    if (lane == 0) {
      float p = 0.0f;
      for (int j = 0; j < N_EXPERTS; j++)
        p += mlip[g * 8 + j] * expf(lg[wv][j] - m) / den;
      out[N_GRAPHS * 16 + g] = p;
    }
  }
}

// ---------------------------------------------------------------------------
extern "C" void kernel_launch(void* const* d_in, const int* in_sizes, int n_in,
                              void* d_out, int out_size, void* d_ws, size_t ws_size,
                              hipStream_t stream) {
  const int*   z     = (const int*)  d_in[0];
  const int*   ei    = (const int*)  d_in[1];
  const float* ew    = (const float*)d_in[2];
  const int*   batch = (const int*)  d_in[3];
  const float* mlip  = (const float*)d_in[4];
  const float* emb   = (const float*)d_in[5];
  const float* fW1   = (const float*)d_in[6];
  const float* fb1   = (const float*)d_in[7];
  const float* fW2   = (const float*)d_in[8];
  const float* fb2   = (const float*)d_in[9];
  const float* dW    = (const float*)d_in[10];
  const float* db    = (const float*)d_in[11];
  const float* uW1   = (const float*)d_in[12];
  const float* ub1   = (const float*)d_in[13];
  const float* uW2   = (const float*)d_in[14];
  const float* ub2   = (const float*)d_in[15];
  const float* gW1   = (const float*)d_in[16];
  const float* gb1   = (const float*)d_in[17];
  const float* gW2   = (const float*)d_in[18];
  const float* gb2   = (const float*)d_in[19];
  const float* gW3   = (const float*)d_in[20];
  const float* gb3   = (const float*)d_in[21];

  const int* src = ei;
  const int* dst = ei + N_EDGES;

  float* ws = (float*)d_ws;
  float*    x        = ws;                          // 6,400,000 f
  __half*   yh       = (__half*)(ws + 6400000);     // 6.4M halves = 3.2M f
  __half*   aggh     = (__half*)(ws + 9600000);     // 3.2M f
  float*    tab      = ws + 12800000;               // 786,624 f
  __half2*  tabP     = (__half2*)(ws + 13586624);   // 786,432 half2 (= f slots)
  float*    pooled   = ws + 14373056;               // 32,768
  float*    counts   = ws + 14405824;               // 512
  int*      rowstart = (int*)(ws + 14406336);       // 100,001
  unsigned* recs     = (unsigned*)(ws + 14506337);  // 1,250,000 -> end ~63 MB
  // preproc-only arrays aliased into aggh's space (rewritten each layer)
  int* deg    = (int*)aggh;
  int* cursor = deg + N_NODES;
  int* bsum   = cursor + N_NODES;

  const int EB = (N_EDGES + 255) / 256;

  // --- CSR build (once) ---
  hipMemsetAsync(deg, 0, N_NODES * sizeof(int), stream);
  hist_kernel<<<EB, 256, 0, stream>>>(dst, deg);
  scan1_kernel<<<NB_SCAN, 256, 0, stream>>>(deg, bsum);
  scan2_kernel<<<1, 512, 0, stream>>>(bsum);
  scan3_kernel<<<NB_SCAN, 256, 0, stream>>>(deg, bsum, rowstart, cursor);
  scatter_kernel<<<EB, 256, 0, stream>>>(src, dst, ew, cursor, recs);

  build_tab<<<N_LAYERS * 1025, 256, 0, stream>>>(fW1, fb1, fW2, fb2, tab);
  pack_tab<<<(N_LAYERS * K_TAB * 64) / 256, 256, 0, stream>>>(tab, tabP);
  embed_kernel<<<(N_NODES * HID + 255) / 256, 256, 0, stream>>>(z, emb, x);

  for (int i = 0; i < N_LAYERS; i++) {
    dense64<<<(N_NODES + 63) / 64, 256, 0, stream>>>(x, dW + i * 4096, db + i * 64, yh);
    gather_kernel<<<(N_NODES + 3) / 4, 256, 0, stream>>>(
        rowstart, recs, tabP + i * K_TAB * 64, yh, aggh);
    update64<<<(N_NODES + 63) / 64, 256, 0, stream>>>(aggh, uW1 + i * 4096, ub1 + i * 64,
                                                      uW2 + i * 4096, ub2 + i * 64, x);
  }

  hipMemsetAsync(pooled, 0, (size_t)(N_GRAPHS * HID + N_GRAPHS) * sizeof(float), stream);
  pool_kernel<<<(N_NODES / 64 + 1 + 3) / 4, 256, 0, stream>>>(x, batch, pooled, counts);
  gate_kernel<<<N_GRAPHS / 4, 256, 0, stream>>>(pooled, counts, mlip,
                                                gW1, gb1, gW2, gb2, gW3, gb3,
                                                (float*)d_out);
}

// Round 4
// 690.728 us; speedup vs baseline: 1.5666x; 1.5666x over previous
//
#include <hip/hip_runtime.h>
#include <hip/hip_fp16.h>
#include <math.h>

#define N_NODES   100000
#define N_EDGES   1250000
#define HID       64
#define N_RBF     32
#define N_GRAPHS  512
#define N_EXPERTS 8
#define N_LAYERS  3
#define CUTOFF    6.0f
#define GATE_IN   72
#define G1_DIM    64
#define G2_DIM    32
#define K_TAB     4096   // lerp intervals
#define NB_SCAN   391    // ceil(N_NODES/256)

// ---------------------------------------------------------------------------
// Filter table (fp32): f_i(w) = silu(rbf(w)@fW1^T+fb1)@fW2^T+fb2
// ---------------------------------------------------------------------------
__global__ __launch_bounds__(256) void build_tab(
    const float* __restrict__ fW1, const float* __restrict__ fb1,
    const float* __restrict__ fW2, const float* __restrict__ fb2,
    float* __restrict__ tab) {
  __shared__ float W1s[64][33];
  __shared__ float W2s[64][65];
  __shared__ float rbfs[4][32];
  __shared__ float h1s[4][64];
  int t = threadIdx.x;
  int wv = t >> 6, lane = t & 63;
  int layer = blockIdx.x / 1025;
  int k = (blockIdx.x % 1025) * 4 + wv;

  for (int i = t; i < 64 * 32; i += 256) W1s[i >> 5][i & 31] = fW1[layer * 2048 + i];
  for (int i = t; i < 64 * 64; i += 256) W2s[i >> 6][i & 63] = fW2[layer * 4096 + i];

  float w = (CUTOFF / (float)K_TAB) * (float)k;
  const float delta = CUTOFF / (float)(N_RBF - 1);
  const float coeff = -0.5f / (delta * delta);
  __syncthreads();

  if (lane < N_RBF) {
    float d = w - delta * (float)lane;
    rbfs[wv][lane] = expf(coeff * d * d);
  }
  __syncthreads();

  float s = fb1[layer * HID + lane];
#pragma unroll
  for (int j = 0; j < N_RBF; j++) s += rbfs[wv][j] * W1s[lane][j];
  h1s[wv][lane] = s / (1.0f + expf(-s));
  __syncthreads();

  float f = fb2[layer * HID + lane];
#pragma unroll
  for (int c = 0; c < HID; c++) f += h1s[wv][c] * W2s[lane][c];
  if (k <= K_TAB) tab[(layer * (K_TAB + 1) + k) * HID + lane] = f;
}

// Pack lerp pairs: tabP[layer][k][lane] = (tab[k], tab[k+1]) as half2
__global__ __launch_bounds__(256) void pack_tab(
    const float* __restrict__ tab, __half2* __restrict__ tabP) {
  int i = blockIdx.x * 256 + threadIdx.x;     // 3*4096*64
  if (i >= N_LAYERS * K_TAB * 64) return;
  int layer = i / (K_TAB * 64);
  int r = i - layer * (K_TAB * 64);
  const float* base = tab + layer * (K_TAB + 1) * 64;
  tabP[i] = __floats2half2_rn(base[r], base[r + 64]);
}

// ---------------------------------------------------------------------------
__global__ __launch_bounds__(256) void embed_kernel(
    const int* __restrict__ z, const float* __restrict__ emb,
    float* __restrict__ x) {
  int i = blockIdx.x * 256 + threadIdx.x;
  if (i < N_NODES * HID) {
    int n = i >> 6, h = i & 63;
    x[i] = emb[z[n] * HID + h];
  }
}

// ---------------------------------------------------------------------------
// CSR build
// ---------------------------------------------------------------------------
__global__ __launch_bounds__(256) void hist_kernel(
    const int* __restrict__ dst, int* __restrict__ deg) {
  int e = blockIdx.x * 256 + threadIdx.x;
  if (e < N_EDGES) atomicAdd(&deg[dst[e]], 1);
}

__global__ __launch_bounds__(256) void scan1_kernel(
    const int* __restrict__ deg, int* __restrict__ bsum) {
  __shared__ int sh[256];
  int t = threadIdx.x;
  int i = blockIdx.x * 256 + t;
  sh[t] = (i < N_NODES) ? deg[i] : 0;
  __syncthreads();
  for (int off = 128; off > 0; off >>= 1) {
    if (t < off) sh[t] += sh[t + off];
    __syncthreads();
  }
  if (t == 0) bsum[blockIdx.x] = sh[0];
}

__global__ __launch_bounds__(512) void scan2_kernel(int* __restrict__ bsum) {
  __shared__ int sh[512];
  int t = threadIdx.x;
  int v = (t < NB_SCAN) ? bsum[t] : 0;
  sh[t] = v;
  __syncthreads();
  for (int off = 1; off < 512; off <<= 1) {
    int add = (t >= off) ? sh[t - off] : 0;
    __syncthreads();
    sh[t] += add;
    __syncthreads();
  }
  if (t < NB_SCAN) bsum[t] = sh[t] - v;   // exclusive
}

__global__ __launch_bounds__(256) void scan3_kernel(
    const int* __restrict__ deg, const int* __restrict__ bsum,
    int* __restrict__ rowstart, int* __restrict__ cursor) {
  __shared__ int sh[256];
  int t = threadIdx.x;
  int i = blockIdx.x * 256 + t;
  int v = (i < N_NODES) ? deg[i] : 0;
  sh[t] = v;
  __syncthreads();
  for (int off = 1; off < 256; off <<= 1) {
    int add = (t >= off) ? sh[t - off] : 0;
    __syncthreads();
    sh[t] += add;
    __syncthreads();
  }
  if (i < N_NODES) {
    int rs = bsum[blockIdx.x] + sh[t] - v;
    rowstart[i] = rs;
    cursor[i] = rs;
  }
  if (i == 0) rowstart[N_NODES] = N_EDGES;
}

__global__ __launch_bounds__(256) void scatter_kernel(
    const int* __restrict__ src, const int* __restrict__ dst,
    const float* __restrict__ ew, int* __restrict__ cursor,
    unsigned* __restrict__ recs) {
  int e = blockIdx.x * 256 + threadIdx.x;
  if (e >= N_EDGES) return;
  int d = dst[e];
  int pos = atomicAdd(&cursor[d], 1);
  float uq = ew[e] * ((float)K_TAB * 8.0f / CUTOFF);
  int wq = (int)(uq + 0.5f);
  if (wq > 32767) wq = 32767;
  recs[pos] = ((unsigned)src[e] << 15) | (unsigned)wq;
}

// ---------------------------------------------------------------------------
// dense64: y[n][o] = (sum_c x[n][c]*W[o][c] + b[o]) -> fp16
// 4x4 register tile; unroll capped at 2 + launch_bounds(256,4) to keep
// VGPR <= 128 (R3's full unroll hit 256 VGPR -> 10% occupancy).
// ---------------------------------------------------------------------------
__global__ __launch_bounds__(256, 4) void dense64(
    const float* __restrict__ x, const float* __restrict__ W,
    const float* __restrict__ b, __half* __restrict__ y) {
  __shared__ float xs[64][68];
  __shared__ float Ws[64][68];
  int t = threadIdx.x;
  int row0 = blockIdx.x * 64;
  int tx = t & 15, ty = t >> 4;

  for (int i = t; i < 4096; i += 256) Ws[i >> 6][i & 63] = W[i];
  for (int i = t; i < 4096; i += 256) {
    int r = i >> 6, gr = row0 + r;
    xs[r][i & 63] = (gr < N_NODES) ? x[gr * 64 + (i & 63)] : 0.0f;
  }
  __syncthreads();

  float acc[4][4];
#pragma unroll
  for (int j = 0; j < 4; j++) {
    float bj = b[tx + 16 * j];
#pragma unroll
    for (int i = 0; i < 4; i++) acc[i][j] = bj;
  }
#pragma unroll 2
  for (int c4 = 0; c4 < 16; c4++) {
    float4 xv[4], wv[4];
#pragma unroll
    for (int i = 0; i < 4; i++) xv[i] = *(const float4*)&xs[ty * 4 + i][c4 * 4];
#pragma unroll
    for (int j = 0; j < 4; j++) wv[j] = *(const float4*)&Ws[tx + 16 * j][c4 * 4];
#pragma unroll
    for (int i = 0; i < 4; i++)
#pragma unroll
      for (int j = 0; j < 4; j++)
        acc[i][j] += xv[i].x * wv[j].x + xv[i].y * wv[j].y +
                     xv[i].z * wv[j].z + xv[i].w * wv[j].w;
  }
#pragma unroll
  for (int i = 0; i < 4; i++) {
    int gr = row0 + ty * 4 + i;
    if (gr < N_NODES)
#pragma unroll
      for (int j = 0; j < 4; j++)
        y[gr * 64 + tx + 16 * j] = __float2half(acc[i][j]);
  }
}

// ---------------------------------------------------------------------------
// update64: x[n] += silu(agg[n]@W1^T+b1)@W2^T+b2   (agg fp16 in)
// ---------------------------------------------------------------------------
__global__ __launch_bounds__(256, 4) void update64(
    const __half* __restrict__ aggh,
    const float* __restrict__ W1, const float* __restrict__ b1,
    const float* __restrict__ W2, const float* __restrict__ b2,
    float* __restrict__ x) {
  __shared__ float as[64][68];
  __shared__ float Ws[64][68];
  int t = threadIdx.x;
  int row0 = blockIdx.x * 64;
  int tx = t & 15, ty = t >> 4;

  for (int i = t; i < 4096; i += 256) Ws[i >> 6][i & 63] = W1[i];
  for (int i = t; i < 2048; i += 256) {
    int r = i >> 5, c2 = (i & 31) * 2, gr = row0 + r;
    __half2 hv = __floats2half2_rn(0.0f, 0.0f);
    if (gr < N_NODES) hv = ((const __half2*)aggh)[gr * 32 + (i & 31)];
    as[r][c2]     = __low2float(hv);
    as[r][c2 + 1] = __high2float(hv);
  }
  __syncthreads();

  float acc[4][4];
#pragma unroll
  for (int j = 0; j < 4; j++) {
    float bj = b1[tx + 16 * j];
#pragma unroll
    for (int i = 0; i < 4; i++) acc[i][j] = bj;
  }
#pragma unroll 2
  for (int c4 = 0; c4 < 16; c4++) {
    float4 xv[4], wv[4];
#pragma unroll
    for (int i = 0; i < 4; i++) xv[i] = *(const float4*)&as[ty * 4 + i][c4 * 4];
#pragma unroll
    for (int j = 0; j < 4; j++) wv[j] = *(const float4*)&Ws[tx + 16 * j][c4 * 4];
#pragma unroll
    for (int i = 0; i < 4; i++)
#pragma unroll
      for (int j = 0; j < 4; j++)
        acc[i][j] += xv[i].x * wv[j].x + xv[i].y * wv[j].y +
                     xv[i].z * wv[j].z + xv[i].w * wv[j].w;
  }
  __syncthreads();   // all reads of as/Ws done
  // h = silu(acc) -> as; stage W2 -> Ws
#pragma unroll
  for (int i = 0; i < 4; i++)
#pragma unroll
    for (int j = 0; j < 4; j++) {
      float s = acc[i][j];
      as[ty * 4 + i][tx + 16 * j] = s / (1.0f + expf(-s));
    }
  for (int i = t; i < 4096; i += 256) Ws[i >> 6][i & 63] = W2[i];
  __syncthreads();

#pragma unroll
  for (int j = 0; j < 4; j++) {
    float bj = b2[tx + 16 * j];
#pragma unroll
    for (int i = 0; i < 4; i++) acc[i][j] = bj;
  }
#pragma unroll 2
  for (int c4 = 0; c4 < 16; c4++) {
    float4 xv[4], wv[4];
#pragma unroll
    for (int i = 0; i < 4; i++) xv[i] = *(const float4*)&as[ty * 4 + i][c4 * 4];
#pragma unroll
    for (int j = 0; j < 4; j++) wv[j] = *(const float4*)&Ws[tx + 16 * j][c4 * 4];
#pragma unroll
    for (int i = 0; i < 4; i++)
#pragma unroll
      for (int j = 0; j < 4; j++)
        acc[i][j] += xv[i].x * wv[j].x + xv[i].y * wv[j].y +
                     xv[i].z * wv[j].z + xv[i].w * wv[j].w;
  }
#pragma unroll
  for (int i = 0; i < 4; i++) {
    int gr = row0 + ty * 4 + i;
    if (gr < N_NODES)
#pragma unroll
      for (int j = 0; j < 4; j++)
        x[gr * 64 + tx + 16 * j] += acc[i][j];
  }
}

// ---------------------------------------------------------------------------
// CSR gather, fp16 payloads, half2-packed lerp table, 4-deep load pipeline.
// ---------------------------------------------------------------------------
__global__ __launch_bounds__(256) void gather_kernel(
    const int* __restrict__ rowstart, const unsigned* __restrict__ recs,
    const __half2* __restrict__ tabP, const __half* __restrict__ yh,
    __half* __restrict__ aggh) {
  int d = blockIdx.x * 4 + (threadIdx.x >> 6);
  int lane = threadIdx.x & 63;
  if (d >= N_NODES) return;
  int b0 = rowstart[d], b1 = rowstart[d + 1];
  float acc = 0.0f;
  int j = b0;
  for (; j + 4 <= b1; j += 4) {
    unsigned u0 = recs[j], u1 = recs[j + 1], u2 = recs[j + 2], u3 = recs[j + 3];
    float y0 = __half2float(yh[(u0 >> 15) * 64 + lane]);
    float y1 = __half2float(yh[(u1 >> 15) * 64 + lane]);
    float y2 = __half2float(yh[(u2 >> 15) * 64 + lane]);
    float y3 = __half2float(yh[(u3 >> 15) * 64 + lane]);
    __half2 p0 = tabP[((u0 & 32767u) >> 3) * 64 + lane];
    __half2 p1 = tabP[((u1 & 32767u) >> 3) * 64 + lane];
    __half2 p2 = tabP[((u2 & 32767u) >> 3) * 64 + lane];
    __half2 p3 = tabP[((u3 & 32767u) >> 3) * 64 + lane];
    float fr0 = (float)(u0 & 7u) * 0.125f;
    float fr1 = (float)(u1 & 7u) * 0.125f;
    float fr2 = (float)(u2 & 7u) * 0.125f;
    float fr3 = (float)(u3 & 7u) * 0.125f;
    float a0 = __low2float(p0), g0 = __high2float(p0);
    float a1 = __low2float(p1), g1 = __high2float(p1);
    float a2 = __low2float(p2), g2 = __high2float(p2);
    float a3 = __low2float(p3), g3 = __high2float(p3);
    acc += y0 * (a0 + (g0 - a0) * fr0);
    acc += y1 * (a1 + (g1 - a1) * fr1);
    acc += y2 * (a2 + (g2 - a2) * fr2);
    acc += y3 * (a3 + (g3 - a3) * fr3);
  }
  for (; j < b1; j++) {
    unsigned u = recs[j];
    float yv = __half2float(yh[(u >> 15) * 64 + lane]);
    __half2 p = tabP[((u & 32767u) >> 3) * 64 + lane];
    float fr = (float)(u & 7u) * 0.125f;
    float a = __low2float(p), g = __high2float(p);
    acc += yv * (a + (g - a) * fr);
  }
  aggh[d * 64 + lane] = __float2half(acc);
}

// ---------------------------------------------------------------------------
__global__ __launch_bounds__(256) void pool_kernel(
    const float* __restrict__ x, const int* __restrict__ batch,
    float* __restrict__ pooled, float* __restrict__ counts) {
  int wid = (blockIdx.x * 256 + threadIdx.x) >> 6;
  int lane = threadIdx.x & 63;
  int n0 = wid * 64;
  if (n0 >= N_NODES) return;
  int n1 = n0 + 64; if (n1 > N_NODES) n1 = N_NODES;
  int curg = batch[n0];
  float acc = 0.0f, cnt = 0.0f;
  for (int n = n0; n < n1; n++) {
    int g = batch[n];
    if (g != curg) {
      unsafeAtomicAdd(&pooled[curg * 64 + lane], acc);
      if (lane == 0) unsafeAtomicAdd(&counts[curg], cnt);
      curg = g; acc = 0.0f; cnt = 0.0f;
    }
    acc += x[n * 64 + lane];
    cnt += 1.0f;
  }
  unsafeAtomicAdd(&pooled[curg * 64 + lane], acc);
  if (lane == 0) unsafeAtomicAdd(&counts[curg], cnt);
}

// ---------------------------------------------------------------------------
__global__ __launch_bounds__(256) void gate_kernel(
    const float* __restrict__ pooled, const float* __restrict__ counts,
    const float* __restrict__ mlip,
    const float* __restrict__ gW1, const float* __restrict__ gb1,
    const float* __restrict__ gW2, const float* __restrict__ gb2,
    const float* __restrict__ gW3, const float* __restrict__ gb3,
    float* __restrict__ out) {
  __shared__ float ins[4][GATE_IN];
  __shared__ float h1s[4][G1_DIM];
  __shared__ float h2s[4][G2_DIM];
  __shared__ float lg[4][N_EXPERTS];
  int wv = threadIdx.x >> 6, lane = threadIdx.x & 63;
  int g = blockIdx.x * 4 + wv;

  float cnt = counts[g];
  if (cnt < 1.0f) cnt = 1.0f;
  ins[wv][lane] = pooled[g * 64 + lane] / cnt;
  if (lane < N_EXPERTS) ins[wv][64 + lane] = mlip[g * N_EXPERTS + lane];
  __syncthreads();

  {
    float s = gb1[lane];
    for (int c = 0; c < GATE_IN; c++) s += ins[wv][c] * gW1[lane * GATE_IN + c];
    h1s[wv][lane] = fmaxf(s, 0.0f);
  }
  __syncthreads();
  if (lane < G2_DIM) {
    float s = gb2[lane];
    for (int c = 0; c < G1_DIM; c++) s += h1s[wv][c] * gW2[lane * G1_DIM + c];
    h2s[wv][lane] = fmaxf(s, 0.0f);
  }
  __syncthreads();
  if (lane < N_EXPERTS) {
    float s = gb3[lane];
    for (int c = 0; c < G2_DIM; c++) s += h2s[wv][c] * gW3[lane * G2_DIM + c];
    lg[wv][lane] = s;
  }
  __syncthreads();
  if (lane < N_EXPERTS) {
    float m = -1e30f;
    for (int j = 0; j < N_EXPERTS; j++) m = fmaxf(m, lg[wv][j]);
    float den = 0.0f;
    for (int j = 0; j < N_EXPERTS; j++) den += expf(lg[wv][j] - m);
    float wgt = expf(lg[wv][lane] - m) / den;
    out[g * 8 + lane] = lg[wv][lane];
    out[N_GRAPHS * 8 + g * 8 + lane] = wgt;
    if (lane == 0) {
      float p = 0.0f;
      for (int j = 0; j < N_EXPERTS; j++)
        p += mlip[g * 8 + j] * expf(lg[wv][j] - m) / den;
      out[N_GRAPHS * 16 + g] = p;
    }
  }
}

// ---------------------------------------------------------------------------
extern "C" void kernel_launch(void* const* d_in, const int* in_sizes, int n_in,
                              void* d_out, int out_size, void* d_ws, size_t ws_size,
                              hipStream_t stream) {
  const int*   z     = (const int*)  d_in[0];
  const int*   ei    = (const int*)  d_in[1];
  const float* ew    = (const float*)d_in[2];
  const int*   batch = (const int*)  d_in[3];
  const float* mlip  = (const float*)d_in[4];
  const float* emb   = (const float*)d_in[5];
  const float* fW1   = (const float*)d_in[6];
  const float* fb1   = (const float*)d_in[7];
  const float* fW2   = (const float*)d_in[8];
  const float* fb2   = (const float*)d_in[9];
  const float* dW    = (const float*)d_in[10];
  const float* db    = (const float*)d_in[11];
  const float* uW1   = (const float*)d_in[12];
  const float* ub1   = (const float*)d_in[13];
  const float* uW2   = (const float*)d_in[14];
  const float* ub2   = (const float*)d_in[15];
  const float* gW1   = (const float*)d_in[16];
  const float* gb1   = (const float*)d_in[17];
  const float* gW2   = (const float*)d_in[18];
  const float* gb2   = (const float*)d_in[19];
  const float* gW3   = (const float*)d_in[20];
  const float* gb3   = (const float*)d_in[21];

  const int* src = ei;
  const int* dst = ei + N_EDGES;

  float* ws = (float*)d_ws;
  float*    x        = ws;                          // 6,400,000 f
  __half*   yh       = (__half*)(ws + 6400000);     // 6.4M halves = 3.2M f
  __half*   aggh     = (__half*)(ws + 9600000);     // 3.2M f
  float*    tab      = ws + 12800000;               // 786,624 f
  __half2*  tabP     = (__half2*)(ws + 13586624);   // 786,432 half2 (= f slots)
  float*    pooled   = ws + 14373056;               // 32,768
  float*    counts   = ws + 14405824;               // 512
  int*      rowstart = (int*)(ws + 14406336);       // 100,001
  unsigned* recs     = (unsigned*)(ws + 14506337);  // 1,250,000 -> end ~63 MB
  // preproc-only arrays aliased into aggh's space (rewritten each layer)
  int* deg    = (int*)aggh;
  int* cursor = deg + N_NODES;
  int* bsum   = cursor + N_NODES;

  const int EB = (N_EDGES + 255) / 256;

  // --- CSR build (once) ---
  hipMemsetAsync(deg, 0, N_NODES * sizeof(int), stream);
  hist_kernel<<<EB, 256, 0, stream>>>(dst, deg);
  scan1_kernel<<<NB_SCAN, 256, 0, stream>>>(deg, bsum);
  scan2_kernel<<<1, 512, 0, stream>>>(bsum);
  scan3_kernel<<<NB_SCAN, 256, 0, stream>>>(deg, bsum, rowstart, cursor);
  scatter_kernel<<<EB, 256, 0, stream>>>(src, dst, ew, cursor, recs);

  build_tab<<<N_LAYERS * 1025, 256, 0, stream>>>(fW1, fb1, fW2, fb2, tab);
  pack_tab<<<(N_LAYERS * K_TAB * 64) / 256, 256, 0, stream>>>(tab, tabP);
  embed_kernel<<<(N_NODES * HID + 255) / 256, 256, 0, stream>>>(z, emb, x);

  for (int i = 0; i < N_LAYERS; i++) {
    dense64<<<(N_NODES + 63) / 64, 256, 0, stream>>>(x, dW + i * 4096, db + i * 64, yh);
    gather_kernel<<<(N_NODES + 3) / 4, 256, 0, stream>>>(
        rowstart, recs, tabP + i * K_TAB * 64, yh, aggh);
    update64<<<(N_NODES + 63) / 64, 256, 0, stream>>>(aggh, uW1 + i * 4096, ub1 + i * 64,
                                                      uW2 + i * 4096, ub2 + i * 64, x);
  }

  hipMemsetAsync(pooled, 0, (size_t)(N_GRAPHS * HID + N_GRAPHS) * sizeof(float), stream);
  pool_kernel<<<(N_NODES / 64 + 1 + 3) / 4, 256, 0, stream>>>(x, batch, pooled, counts);
  gate_kernel<<<N_GRAPHS / 4, 256, 0, stream>>>(pooled, counts, mlip,
                                                gW1, gb1, gW2, gb2, gW3, gb3,
                                                (float*)d_out);
}

// Round 5
// 632.007 us; speedup vs baseline: 1.7122x; 1.0929x over previous
//
#include <hip/hip_runtime.h>
#include <hip/hip_fp16.h>
#include <math.h>

#define N_NODES   100000
#define N_EDGES   1250000
#define HID       64
#define N_RBF     32
#define N_GRAPHS  512
#define N_EXPERTS 8
#define N_LAYERS  3
#define CUTOFF    6.0f
#define GATE_IN   72
#define G1_DIM    64
#define G2_DIM    32
#define K_TAB     4096   // lerp intervals
#define NB_SCAN   391    // ceil(N_NODES/256)
#define N_BUCKET  391    // 256-node buckets
#define BUCKET_CAP 4608  // Poisson(3200) + 25 sigma
#define CHUNK_A   8192

// e5m2 encode: fp16 bits, round-half-up in magnitude, keep high byte.
__device__ __forceinline__ unsigned char enc8(float v) {
  unsigned short u = __half_as_ushort(__float2half(v));
  return (unsigned char)((u + 0x80u) >> 8);
}
__device__ __forceinline__ float dec8(unsigned int b) {
  return __half2float(__ushort_as_half((unsigned short)(b << 8)));
}

// ---------------------------------------------------------------------------
// Filter table (fp32): f_i(w) = silu(rbf(w)@fW1^T+fb1)@fW2^T+fb2
// ---------------------------------------------------------------------------
__global__ __launch_bounds__(256) void build_tab(
    const float* __restrict__ fW1, const float* __restrict__ fb1,
    const float* __restrict__ fW2, const float* __restrict__ fb2,
    float* __restrict__ tab) {
  __shared__ float W1s[64][33];
  __shared__ float W2s[64][65];
  __shared__ float rbfs[4][32];
  __shared__ float h1s[4][64];
  int t = threadIdx.x;
  int wv = t >> 6, lane = t & 63;
  int layer = blockIdx.x / 1025;
  int k = (blockIdx.x % 1025) * 4 + wv;

  for (int i = t; i < 64 * 32; i += 256) W1s[i >> 5][i & 31] = fW1[layer * 2048 + i];
  for (int i = t; i < 64 * 64; i += 256) W2s[i >> 6][i & 63] = fW2[layer * 4096 + i];

  float w = (CUTOFF / (float)K_TAB) * (float)k;
  const float delta = CUTOFF / (float)(N_RBF - 1);
  const float coeff = -0.5f / (delta * delta);
  __syncthreads();

  if (lane < N_RBF) {
    float d = w - delta * (float)lane;
    rbfs[wv][lane] = expf(coeff * d * d);
  }
  __syncthreads();

  float s = fb1[layer * HID + lane];
#pragma unroll
  for (int j = 0; j < N_RBF; j++) s += rbfs[wv][j] * W1s[lane][j];
  h1s[wv][lane] = s / (1.0f + expf(-s));
  __syncthreads();

  float f = fb2[layer * HID + lane];
#pragma unroll
  for (int c = 0; c < HID; c++) f += h1s[wv][c] * W2s[lane][c];
  if (k <= K_TAB) tab[(layer * (K_TAB + 1) + k) * HID + lane] = f;
}

// Pack lerp pairs as 2x e5m2 bytes: tabP8[layer][k][lane] = (f[k], f[k+1])
__global__ __launch_bounds__(256) void pack_tab8(
    const float* __restrict__ tab, unsigned short* __restrict__ tabP8) {
  int i = blockIdx.x * 256 + threadIdx.x;     // 3*4096*64
  if (i >= N_LAYERS * K_TAB * 64) return;
  int layer = i / (K_TAB * 64);
  int r = i - layer * (K_TAB * 64);
  const float* base = tab + layer * (K_TAB + 1) * 64;
  tabP8[i] = (unsigned short)enc8(base[r]) |
             ((unsigned short)enc8(base[r + 64]) << 8);
}

// ---------------------------------------------------------------------------
__global__ __launch_bounds__(256) void embed_kernel(
    const int* __restrict__ z, const float* __restrict__ emb,
    float* __restrict__ x) {
  int i = blockIdx.x * 256 + threadIdx.x;
  if (i < N_NODES * HID) {
    int n = i >> 6, h = i & 63;
    x[i] = emb[z[n] * HID + h];
  }
}

// ---------------------------------------------------------------------------
// CSR build: histogram -> scan -> rowstart
// ---------------------------------------------------------------------------
__global__ __launch_bounds__(256) void hist_kernel(
    const int* __restrict__ dst, int* __restrict__ deg) {
  int e = blockIdx.x * 256 + threadIdx.x;
  if (e < N_EDGES) atomicAdd(&deg[dst[e]], 1);
}

__global__ __launch_bounds__(256) void scan1_kernel(
    const int* __restrict__ deg, int* __restrict__ bsum) {
  __shared__ int sh[256];
  int t = threadIdx.x;
  int i = blockIdx.x * 256 + t;
  sh[t] = (i < N_NODES) ? deg[i] : 0;
  __syncthreads();
  for (int off = 128; off > 0; off >>= 1) {
    if (t < off) sh[t] += sh[t + off];
    __syncthreads();
  }
  if (t == 0) bsum[blockIdx.x] = sh[0];
}

__global__ __launch_bounds__(512) void scan2_kernel(int* __restrict__ bsum) {
  __shared__ int sh[512];
  int t = threadIdx.x;
  int v = (t < NB_SCAN) ? bsum[t] : 0;
  sh[t] = v;
  __syncthreads();
  for (int off = 1; off < 512; off <<= 1) {
    int add = (t >= off) ? sh[t - off] : 0;
    __syncthreads();
    sh[t] += add;
    __syncthreads();
  }
  if (t < NB_SCAN) bsum[t] = sh[t] - v;   // exclusive
}

__global__ __launch_bounds__(256) void scan3_kernel(
    const int* __restrict__ deg, const int* __restrict__ bsum,
    int* __restrict__ rowstart, int* __restrict__ cursor) {
  __shared__ int sh[256];
  int t = threadIdx.x;
  int i = blockIdx.x * 256 + t;
  int v = (i < N_NODES) ? deg[i] : 0;
  sh[t] = v;
  __syncthreads();
  for (int off = 1; off < 256; off <<= 1) {
    int add = (t >= off) ? sh[t - off] : 0;
    __syncthreads();
    sh[t] += add;
    __syncthreads();
  }
  if (i < N_NODES) {
    int rs = bsum[blockIdx.x] + sh[t] - v;
    rowstart[i] = rs;
    cursor[i] = rs;   // for sortB's (never-taken) overflow fallback
  }
  if (i == 0) rowstart[N_NODES] = N_EDGES;
}

__global__ __launch_bounds__(512) void gcur_init(
    const int* __restrict__ rowstart, int* __restrict__ gcur) {
  int t = threadIdx.x;
  if (t < N_BUCKET) gcur[t] = rowstart[t * 256];
}

// ---------------------------------------------------------------------------
// Phase A: partition edges into 391 buckets of 256 nodes; LDS histogram per
// block + one global-cursor reservation per (block,bucket) -> contiguous runs
// of ~21 recs -> near-full-line writes (vs R4's 16x write amplification).
// stage8[pos] = {rec, dst}, rec = (src<<15)|wq.
// ---------------------------------------------------------------------------
__global__ __launch_bounds__(256) void partitionA(
    const int* __restrict__ src, const int* __restrict__ dst,
    const float* __restrict__ ew, int* __restrict__ gcur,
    uint2* __restrict__ stage8) {
  __shared__ int hist[N_BUCKET];
  __shared__ int base[N_BUCKET];
  int t = threadIdx.x;
  int e0 = blockIdx.x * CHUNK_A;
  int e1 = e0 + CHUNK_A; if (e1 > N_EDGES) e1 = N_EDGES;

  for (int i = t; i < N_BUCKET; i += 256) hist[i] = 0;
  __syncthreads();
  for (int e = e0 + t; e < e1; e += 256)
    atomicAdd(&hist[dst[e] >> 8], 1);
  __syncthreads();
  for (int i = t; i < N_BUCKET; i += 256) {
    int c = hist[i];
    base[i] = c ? atomicAdd(&gcur[i], c) : 0;
    hist[i] = 0;
  }
  __syncthreads();
  for (int e = e0 + t; e < e1; e += 256) {
    int d = dst[e];
    int b = d >> 8;
    int r = atomicAdd(&hist[b], 1);
    float uq = ew[e] * ((float)K_TAB * 8.0f / CUTOFF);
    int wq = (int)(uq + 0.5f);
    if (wq > 32767) wq = 32767;
    unsigned rec = ((unsigned)src[e] << 15) | (unsigned)wq;
    stage8[base[b] + r] = make_uint2(rec, (unsigned)d);
  }
}

// ---------------------------------------------------------------------------
// Phase B: one block per bucket. LDS counting "sort" to exact CSR grouping
// (intra-node order arbitrary - sum is commutative), coalesced write-out.
// ---------------------------------------------------------------------------
__global__ __launch_bounds__(256) void sortB(
    const int* __restrict__ rowstart, const uint2* __restrict__ stage8,
    int* __restrict__ cursor, unsigned* __restrict__ recs) {
  __shared__ int rs[257];
  __shared__ int cnt[256];
  __shared__ unsigned dest[BUCKET_CAP];
  int t = threadIdx.x;
  int node0 = blockIdx.x * 256;
  {
    int n = node0 + t;
    rs[t] = rowstart[n > N_NODES ? N_NODES : n];
    if (t == 0) {
      int n2 = node0 + 256;
      rs[256] = rowstart[n2 > N_NODES ? N_NODES : n2];
    }
  }
  cnt[t] = 0;
  __syncthreads();
  int rs0 = rs[0], rs1 = rs[256];
  int total = rs1 - rs0;

  if (total <= BUCKET_CAP) {
    for (int k = t; k < total; k += 256) {
      uint2 v = stage8[rs0 + k];
      int ln = (int)v.y - node0;
      int r = atomicAdd(&cnt[ln], 1);
      dest[(rs[ln] - rs0) + r] = v.x;
    }
    __syncthreads();
    for (int k = t; k < total; k += 256) recs[rs0 + k] = dest[k];
  } else {
    // overflow fallback (deterministically never taken at 25 sigma)
    for (int k = t; k < total; k += 256) {
      uint2 v = stage8[rs0 + k];
      int pos = atomicAdd(&cursor[v.y], 1);
      recs[pos] = v.x;
    }
  }
}

// ---------------------------------------------------------------------------
// dense64: y[n][o] = (sum_c x[n][c]*W[o][c] + b[o]) -> e5m2 byte
// ---------------------------------------------------------------------------
__global__ __launch_bounds__(256, 4) void dense64(
    const float* __restrict__ x, const float* __restrict__ W,
    const float* __restrict__ b, unsigned char* __restrict__ yb) {
  __shared__ float xs[64][68];
  __shared__ float Ws[64][68];
  int t = threadIdx.x;
  int row0 = blockIdx.x * 64;
  int tx = t & 15, ty = t >> 4;

  for (int i = t; i < 4096; i += 256) Ws[i >> 6][i & 63] = W[i];
  for (int i = t; i < 4096; i += 256) {
    int r = i >> 6, gr = row0 + r;
    xs[r][i & 63] = (gr < N_NODES) ? x[gr * 64 + (i & 63)] : 0.0f;
  }
  __syncthreads();

  float acc[4][4];
#pragma unroll
  for (int j = 0; j < 4; j++) {
    float bj = b[tx + 16 * j];
#pragma unroll
    for (int i = 0; i < 4; i++) acc[i][j] = bj;
  }
#pragma unroll 2
  for (int c4 = 0; c4 < 16; c4++) {
    float4 xv[4], wv[4];
#pragma unroll
    for (int i = 0; i < 4; i++) xv[i] = *(const float4*)&xs[ty * 4 + i][c4 * 4];
#pragma unroll
    for (int j = 0; j < 4; j++) wv[j] = *(const float4*)&Ws[tx + 16 * j][c4 * 4];
#pragma unroll
    for (int i = 0; i < 4; i++)
#pragma unroll
      for (int j = 0; j < 4; j++)
        acc[i][j] += xv[i].x * wv[j].x + xv[i].y * wv[j].y +
                     xv[i].z * wv[j].z + xv[i].w * wv[j].w;
  }
#pragma unroll
  for (int i = 0; i < 4; i++) {
    int gr = row0 + ty * 4 + i;
    if (gr < N_NODES)
#pragma unroll
      for (int j = 0; j < 4; j++)
        yb[gr * 64 + tx + 16 * j] = enc8(acc[i][j]);
  }
}

// ---------------------------------------------------------------------------
// update64: x[n] += silu(agg[n]@W1^T+b1)@W2^T+b2   (agg fp16 in)
// ---------------------------------------------------------------------------
__global__ __launch_bounds__(256, 4) void update64(
    const __half* __restrict__ aggh,
    const float* __restrict__ W1, const float* __restrict__ b1,
    const float* __restrict__ W2, const float* __restrict__ b2,
    float* __restrict__ x) {
  __shared__ float as[64][68];
  __shared__ float Ws[64][68];
  int t = threadIdx.x;
  int row0 = blockIdx.x * 64;
  int tx = t & 15, ty = t >> 4;

  for (int i = t; i < 4096; i += 256) Ws[i >> 6][i & 63] = W1[i];
  for (int i = t; i < 2048; i += 256) {
    int r = i >> 5, c2 = (i & 31) * 2, gr = row0 + r;
    __half2 hv = __floats2half2_rn(0.0f, 0.0f);
    if (gr < N_NODES) hv = ((const __half2*)aggh)[gr * 32 + (i & 31)];
    as[r][c2]     = __low2float(hv);
    as[r][c2 + 1] = __high2float(hv);
  }
  __syncthreads();

  float acc[4][4];
#pragma unroll
  for (int j = 0; j < 4; j++) {
    float bj = b1[tx + 16 * j];
#pragma unroll
    for (int i = 0; i < 4; i++) acc[i][j] = bj;
  }
#pragma unroll 2
  for (int c4 = 0; c4 < 16; c4++) {
    float4 xv[4], wv[4];
#pragma unroll
    for (int i = 0; i < 4; i++) xv[i] = *(const float4*)&as[ty * 4 + i][c4 * 4];
#pragma unroll
    for (int j = 0; j < 4; j++) wv[j] = *(const float4*)&Ws[tx + 16 * j][c4 * 4];
#pragma unroll
    for (int i = 0; i < 4; i++)
#pragma unroll
      for (int j = 0; j < 4; j++)
        acc[i][j] += xv[i].x * wv[j].x + xv[i].y * wv[j].y +
                     xv[i].z * wv[j].z + xv[i].w * wv[j].w;
  }
  __syncthreads();
#pragma unroll
  for (int i = 0; i < 4; i++)
#pragma unroll
    for (int j = 0; j < 4; j++) {
      float s = acc[i][j];
      as[ty * 4 + i][tx + 16 * j] = s / (1.0f + expf(-s));
    }
  for (int i = t; i < 4096; i += 256) Ws[i >> 6][i & 63] = W2[i];
  __syncthreads();

#pragma unroll
  for (int j = 0; j < 4; j++) {
    float bj = b2[tx + 16 * j];
#pragma unroll
    for (int i = 0; i < 4; i++) acc[i][j] = bj;
  }
#pragma unroll 2
  for (int c4 = 0; c4 < 16; c4++) {
    float4 xv[4], wv[4];
#pragma unroll
    for (int i = 0; i < 4; i++) xv[i] = *(const float4*)&as[ty * 4 + i][c4 * 4];
#pragma unroll
    for (int j = 0; j < 4; j++) wv[j] = *(const float4*)&Ws[tx + 16 * j][c4 * 4];
#pragma unroll
    for (int i = 0; i < 4; i++)
#pragma unroll
      for (int j = 0; j < 4; j++)
        acc[i][j] += xv[i].x * wv[j].x + xv[i].y * wv[j].y +
                     xv[i].z * wv[j].z + xv[i].w * wv[j].w;
  }
#pragma unroll
  for (int i = 0; i < 4; i++) {
    int gr = row0 + ty * 4 + i;
    if (gr < N_NODES)
#pragma unroll
      for (int j = 0; j < 4; j++)
        x[gr * 64 + tx + 16 * j] += acc[i][j];
  }
}

// ---------------------------------------------------------------------------
// CSR gather: e5m2 y (64 B/edge) + e5m2 lerp-pair table (2 B/lane),
// 4-deep load pipeline, one wave per node.
// ---------------------------------------------------------------------------
__global__ __launch_bounds__(256) void gather_kernel(
    const int* __restrict__ rowstart, const unsigned* __restrict__ recs,
    const unsigned short* __restrict__ tabP8,
    const unsigned char* __restrict__ yb,
    __half* __restrict__ aggh) {
  int d = blockIdx.x * 4 + (threadIdx.x >> 6);
  int lane = threadIdx.x & 63;
  if (d >= N_NODES) return;
  int b0 = rowstart[d], b1 = rowstart[d + 1];
  float acc = 0.0f;
  int j = b0;
  for (; j + 4 <= b1; j += 4) {
    unsigned u0 = recs[j], u1 = recs[j + 1], u2 = recs[j + 2], u3 = recs[j + 3];
    unsigned yb0 = yb[(u0 >> 15) * 64 + lane];
    unsigned yb1 = yb[(u1 >> 15) * 64 + lane];
    unsigned yb2 = yb[(u2 >> 15) * 64 + lane];
    unsigned yb3 = yb[(u3 >> 15) * 64 + lane];
    unsigned p0 = tabP8[((u0 & 32767u) >> 3) * 64 + lane];
    unsigned p1 = tabP8[((u1 & 32767u) >> 3) * 64 + lane];
    unsigned p2 = tabP8[((u2 & 32767u) >> 3) * 64 + lane];
    unsigned p3 = tabP8[((u3 & 32767u) >> 3) * 64 + lane];
    float fr0 = (float)(u0 & 7u) * 0.125f;
    float fr1 = (float)(u1 & 7u) * 0.125f;
    float fr2 = (float)(u2 & 7u) * 0.125f;
    float fr3 = (float)(u3 & 7u) * 0.125f;
    float a0 = dec8(p0 & 0xffu), g0 = dec8(p0 >> 8);
    float a1 = dec8(p1 & 0xffu), g1 = dec8(p1 >> 8);
    float a2 = dec8(p2 & 0xffu), g2 = dec8(p2 >> 8);
    float a3 = dec8(p3 & 0xffu), g3 = dec8(p3 >> 8);
    acc += dec8(yb0) * (a0 + (g0 - a0) * fr0);
    acc += dec8(yb1) * (a1 + (g1 - a1) * fr1);
    acc += dec8(yb2) * (a2 + (g2 - a2) * fr2);
    acc += dec8(yb3) * (a3 + (g3 - a3) * fr3);
  }
  for (; j < b1; j++) {
    unsigned u = recs[j];
    unsigned ybv = yb[(u >> 15) * 64 + lane];
    unsigned p = tabP8[((u & 32767u) >> 3) * 64 + lane];
    float fr = (float)(u & 7u) * 0.125f;
    float a = dec8(p & 0xffu), g = dec8(p >> 8);
    acc += dec8(ybv) * (a + (g - a) * fr);
  }
  aggh[d * 64 + lane] = __float2half(acc);
}

// ---------------------------------------------------------------------------
__global__ __launch_bounds__(256) void pool_kernel(
    const float* __restrict__ x, const int* __restrict__ batch,
    float* __restrict__ pooled, float* __restrict__ counts) {
  int wid = (blockIdx.x * 256 + threadIdx.x) >> 6;
  int lane = threadIdx.x & 63;
  int n0 = wid * 64;
  if (n0 >= N_NODES) return;
  int n1 = n0 + 64; if (n1 > N_NODES) n1 = N_NODES;
  int curg = batch[n0];
  float acc = 0.0f, cnt = 0.0f;
  for (int n = n0; n < n1; n++) {
    int g = batch[n];
    if (g != curg) {
      unsafeAtomicAdd(&pooled[curg * 64 + lane], acc);
      if (lane == 0) unsafeAtomicAdd(&counts[curg], cnt);
      curg = g; acc = 0.0f; cnt = 0.0f;
    }
    acc += x[n * 64 + lane];
    cnt += 1.0f;
  }
  unsafeAtomicAdd(&pooled[curg * 64 + lane], acc);
  if (lane == 0) unsafeAtomicAdd(&counts[curg], cnt);
}

// ---------------------------------------------------------------------------
__global__ __launch_bounds__(256) void gate_kernel(
    const float* __restrict__ pooled, const float* __restrict__ counts,
    const float* __restrict__ mlip,
    const float* __restrict__ gW1, const float* __restrict__ gb1,
    const float* __restrict__ gW2, const float* __restrict__ gb2,
    const float* __restrict__ gW3, const float* __restrict__ gb3,
    float* __restrict__ out) {
  __shared__ float ins[4][GATE_IN];
  __shared__ float h1s[4][G1_DIM];
  __shared__ float h2s[4][G2_DIM];
  __shared__ float lg[4][N_EXPERTS];
  int wv = threadIdx.x >> 6, lane = threadIdx.x & 63;
  int g = blockIdx.x * 4 + wv;

  float cnt = counts[g];
  if (cnt < 1.0f) cnt = 1.0f;
  ins[wv][lane] = pooled[g * 64 + lane] / cnt;
  if (lane < N_EXPERTS) ins[wv][64 + lane] = mlip[g * N_EXPERTS + lane];
  __syncthreads();

  {
    float s = gb1[lane];
    for (int c = 0; c < GATE_IN; c++) s += ins[wv][c] * gW1[lane * GATE_IN + c];
    h1s[wv][lane] = fmaxf(s, 0.0f);
  }
  __syncthreads();
  if (lane < G2_DIM) {
    float s = gb2[lane];
    for (int c = 0; c < G1_DIM; c++) s += h1s[wv][c] * gW2[lane * G1_DIM + c];
    h2s[wv][lane] = fmaxf(s, 0.0f);
  }
  __syncthreads();
  if (lane < N_EXPERTS) {
    float s = gb3[lane];
    for (int c = 0; c < G2_DIM; c++) s += h2s[wv][c] * gW3[lane * G2_DIM + c];
    lg[wv][lane] = s;
  }
  __syncthreads();
  if (lane < N_EXPERTS) {
    float m = -1e30f;
    for (int j = 0; j < N_EXPERTS; j++) m = fmaxf(m, lg[wv][j]);
    float den = 0.0f;
    for (int j = 0; j < N_EXPERTS; j++) den += expf(lg[wv][j] - m);
    float wgt = expf(lg[wv][lane] - m) / den;
    out[g * 8 + lane] = lg[wv][lane];
    out[N_GRAPHS * 8 + g * 8 + lane] = wgt;
    if (lane == 0) {
      float p = 0.0f;
      for (int j = 0; j < N_EXPERTS; j++)
        p += mlip[g * 8 + j] * expf(lg[wv][j] - m) / den;
      out[N_GRAPHS * 16 + g] = p;
    }
  }
}

// ---------------------------------------------------------------------------
extern "C" void kernel_launch(void* const* d_in, const int* in_sizes, int n_in,
                              void* d_out, int out_size, void* d_ws, size_t ws_size,
                              hipStream_t stream) {
  const int*   z     = (const int*)  d_in[0];
  const int*   ei    = (const int*)  d_in[1];
  const float* ew    = (const float*)d_in[2];
  const int*   batch = (const int*)  d_in[3];
  const float* mlip  = (const float*)d_in[4];
  const float* emb   = (const float*)d_in[5];
  const float* fW1   = (const float*)d_in[6];
  const float* fb1   = (const float*)d_in[7];
  const float* fW2   = (const float*)d_in[8];
  const float* fb2   = (const float*)d_in[9];
  const float* dW    = (const float*)d_in[10];
  const float* db    = (const float*)d_in[11];
  const float* uW1   = (const float*)d_in[12];
  const float* ub1   = (const float*)d_in[13];
  const float* uW2   = (const float*)d_in[14];
  const float* ub2   = (const float*)d_in[15];
  const float* gW1   = (const float*)d_in[16];
  const float* gb1   = (const float*)d_in[17];
  const float* gW2   = (const float*)d_in[18];
  const float* gb2   = (const float*)d_in[19];
  const float* gW3   = (const float*)d_in[20];
  const float* gb3   = (const float*)d_in[21];

  const int* src = ei;
  const int* dst = ei + N_EDGES;

  float* ws = (float*)d_ws;
  float*          x        = ws;                             // [0, 6.4M)
  unsigned char*  yb       = (unsigned char*)(ws + 6400000); // 6.4MB = 1.6M f
  __half*         aggh     = (__half*)(ws + 8000000);        // 12.8MB = 3.2M f
  float*          tab      = ws + 11200000;                  // 786,624 f
  unsigned short* tabP8    = (unsigned short*)(ws + 11986624); // 786,432 us = 393,216 f
  float*          pooled   = ws + 12379840;                  // 32,768
  float*          counts   = ws + 12412608;                  // 512
  int*            rowstart = (int*)(ws + 12413120);          // 100,001
  unsigned*       recs     = (unsigned*)(ws + 12513121);     // 1,250,000
  int*            gcur     = (int*)(ws + 13763121);          // 391
  // preproc-only arrays aliased into aggh's 3.2M-float region
  int*   deg    = (int*)aggh;                 // 100,000
  int*   cursor = deg + 100000;               // 100,000
  int*   bsum   = cursor + 100000;            // 391
  uint2* stage8 = (uint2*)(deg + 200392);     // 1.25M uint2 = 2.5M f, ends < 3.2M

  const int EB = (N_EDGES + 255) / 256;

  // --- CSR build (once per launch) ---
  hipMemsetAsync(deg, 0, N_NODES * sizeof(int), stream);
  hist_kernel<<<EB, 256, 0, stream>>>(dst, deg);
  scan1_kernel<<<NB_SCAN, 256, 0, stream>>>(deg, bsum);
  scan2_kernel<<<1, 512, 0, stream>>>(bsum);
  scan3_kernel<<<NB_SCAN, 256, 0, stream>>>(deg, bsum, rowstart, cursor);
  gcur_init<<<1, 512, 0, stream>>>(rowstart, gcur);
  partitionA<<<(N_EDGES + CHUNK_A - 1) / CHUNK_A, 256, 0, stream>>>(
      src, dst, ew, gcur, stage8);
  sortB<<<N_BUCKET, 256, 0, stream>>>(rowstart, stage8, cursor, recs);

  build_tab<<<N_LAYERS * 1025, 256, 0, stream>>>(fW1, fb1, fW2, fb2, tab);
  pack_tab8<<<(N_LAYERS * K_TAB * 64) / 256, 256, 0, stream>>>(tab, tabP8);
  embed_kernel<<<(N_NODES * HID + 255) / 256, 256, 0, stream>>>(z, emb, x);

  for (int i = 0; i < N_LAYERS; i++) {
    dense64<<<(N_NODES + 63) / 64, 256, 0, stream>>>(x, dW + i * 4096, db + i * 64, yb);
    gather_kernel<<<(N_NODES + 3) / 4, 256, 0, stream>>>(
        rowstart, recs, tabP8 + i * K_TAB * 64, yb, aggh);
    update64<<<(N_NODES + 63) / 64, 256, 0, stream>>>(aggh, uW1 + i * 4096, ub1 + i * 64,
                                                      uW2 + i * 4096, ub2 + i * 64, x);
  }

  hipMemsetAsync(pooled, 0, (size_t)(N_GRAPHS * HID + N_GRAPHS) * sizeof(float), stream);
  pool_kernel<<<(N_NODES / 64 + 1 + 3) / 4, 256, 0, stream>>>(x, batch, pooled, counts);
  gate_kernel<<<N_GRAPHS / 4, 256, 0, stream>>>(pooled, counts, mlip,
                                                gW1, gb1, gW2, gb2, gW3, gb3,
                                                (float*)d_out);
}

// Round 6
// 550.663 us; speedup vs baseline: 1.9651x; 1.1477x over previous
//
#include <hip/hip_runtime.h>
#include <hip/hip_fp16.h>
#include <math.h>

#define N_NODES   100000
#define N_EDGES   1250000
#define HID       64
#define N_RBF     32
#define N_GRAPHS  512
#define N_EXPERTS 8
#define N_LAYERS  3
#define CUTOFF    6.0f
#define GATE_IN   72
#define G1_DIM    64
#define G2_DIM    32
#define K_TAB     4096   // lerp intervals
#define N_BUCKET  391    // 256-node buckets
#define BUCKET_CAP 4608  // mean 3200, sigma 56.5 -> +25 sigma
#define CHUNK_A   8192

// e5m2 encode: fp16 bits, round-half-up in magnitude, keep high byte.
__device__ __forceinline__ unsigned enc8(float v) {
  unsigned short u = __half_as_ushort(__float2half(v));
  return (unsigned)((unsigned short)(u + 0x80u) >> 8);
}
__device__ __forceinline__ float dec8(unsigned b) {
  return __half2float(__ushort_as_half((unsigned short)(b << 8)));
}

// ---------------------------------------------------------------------------
// Filter table (fp32): f_i(w) = silu(rbf(w)@fW1^T+fb1)@fW2^T+fb2
// ---------------------------------------------------------------------------
__global__ __launch_bounds__(256) void build_tab(
    const float* __restrict__ fW1, const float* __restrict__ fb1,
    const float* __restrict__ fW2, const float* __restrict__ fb2,
    float* __restrict__ tab) {
  __shared__ float W1s[64][33];
  __shared__ float W2s[64][65];
  __shared__ float rbfs[4][32];
  __shared__ float h1s[4][64];
  int t = threadIdx.x;
  int wv = t >> 6, lane = t & 63;
  int layer = blockIdx.x / 1025;
  int k = (blockIdx.x % 1025) * 4 + wv;

  for (int i = t; i < 64 * 32; i += 256) W1s[i >> 5][i & 31] = fW1[layer * 2048 + i];
  for (int i = t; i < 64 * 64; i += 256) W2s[i >> 6][i & 63] = fW2[layer * 4096 + i];

  float w = (CUTOFF / (float)K_TAB) * (float)k;
  const float delta = CUTOFF / (float)(N_RBF - 1);
  const float coeff = -0.5f / (delta * delta);
  __syncthreads();

  if (lane < N_RBF) {
    float d = w - delta * (float)lane;
    rbfs[wv][lane] = expf(coeff * d * d);
  }
  __syncthreads();

  float s = fb1[layer * HID + lane];
#pragma unroll
  for (int j = 0; j < N_RBF; j++) s += rbfs[wv][j] * W1s[lane][j];
  h1s[wv][lane] = s / (1.0f + expf(-s));
  __syncthreads();

  float f = fb2[layer * HID + lane];
#pragma unroll
  for (int c = 0; c < HID; c++) f += h1s[wv][c] * W2s[lane][c];
  if (k <= K_TAB) tab[(layer * (K_TAB + 1) + k) * HID + lane] = f;
}

// Pack lerp pairs as 2x e5m2 bytes: tabP8[layer][k][lane] = (f[k], f[k+1])
__global__ __launch_bounds__(256) void pack_tab8(
    const float* __restrict__ tab, unsigned short* __restrict__ tabP8) {
  int i = blockIdx.x * 256 + threadIdx.x;     // 3*4096*64
  if (i >= N_LAYERS * K_TAB * 64) return;
  int layer = i / (K_TAB * 64);
  int r = i - layer * (K_TAB * 64);
  const float* base = tab + layer * (K_TAB + 1) * 64;
  tabP8[i] = (unsigned short)(enc8(base[r]) | (enc8(base[r + 64]) << 8));
}

// ---------------------------------------------------------------------------
__global__ __launch_bounds__(256) void embed_kernel(
    const int* __restrict__ z, const float* __restrict__ emb,
    float* __restrict__ x) {
  int i = blockIdx.x * 256 + threadIdx.x;
  if (i < N_NODES * HID) {
    int n = i >> 6, h = i & 63;
    x[i] = emb[z[n] * HID + h];
  }
}

// ---------------------------------------------------------------------------
// Phase A: partition edges into 391 fixed-capacity buckets (256 nodes each).
// Per-block LDS histogram + one global reservation per (block,bucket).
// stage[b*CAP + pos] = {rec, dst}, rec = (src<<15)|wq.
// ---------------------------------------------------------------------------
__global__ __launch_bounds__(256) void partitionA(
    const int* __restrict__ src, const int* __restrict__ dst,
    const float* __restrict__ ew, int* __restrict__ gcnt,
    uint2* __restrict__ stage) {
  __shared__ int hist[N_BUCKET];
  __shared__ int base[N_BUCKET];
  int t = threadIdx.x;
  int e0 = blockIdx.x * CHUNK_A;
  int e1 = e0 + CHUNK_A; if (e1 > N_EDGES) e1 = N_EDGES;

  for (int i = t; i < N_BUCKET; i += 256) hist[i] = 0;
  __syncthreads();
  for (int e = e0 + t; e < e1; e += 256)
    atomicAdd(&hist[dst[e] >> 8], 1);
  __syncthreads();
  for (int i = t; i < N_BUCKET; i += 256) {
    int c = hist[i];
    base[i] = c ? atomicAdd(&gcnt[i], c) : 0;
    hist[i] = 0;
  }
  __syncthreads();
  for (int e = e0 + t; e < e1; e += 256) {
    int d = dst[e];
    int b = d >> 8;
    int r = base[b] + atomicAdd(&hist[b], 1);
    if (r < BUCKET_CAP) {
      float uq = ew[e] * ((float)K_TAB * 8.0f / CUTOFF);
      int wq = (int)(uq + 0.5f);
      if (wq > 32767) wq = 32767;
      stage[(size_t)b * BUCKET_CAP + r] =
          make_uint2(((unsigned)src[e] << 15) | (unsigned)wq, (unsigned)d);
    }
  }
}

// Scan bucket counts -> bucket bases; also rowstart[N_NODES].
__global__ __launch_bounds__(512) void bscan_kernel(
    const int* __restrict__ gcnt, int* __restrict__ bbase,
    int* __restrict__ rowstart) {
  __shared__ int sh[512];
  int t = threadIdx.x;
  int v = 0;
  if (t < N_BUCKET) {
    v = gcnt[t];
    if (v > BUCKET_CAP) v = BUCKET_CAP;
  }
  sh[t] = v;
  __syncthreads();
  for (int off = 1; off < 512; off <<= 1) {
    int add = (t >= off) ? sh[t - off] : 0;
    __syncthreads();
    sh[t] += add;
    __syncthreads();
  }
  if (t < N_BUCKET) bbase[t] = sh[t] - v;
  if (t == N_BUCKET - 1) {
    bbase[N_BUCKET] = sh[t];
    rowstart[N_NODES] = sh[t];
  }
}

// ---------------------------------------------------------------------------
// Phase B: one block per bucket. LDS count -> scan (emits rowstart for its
// 256 nodes) -> place into CSR order in LDS -> coalesced write-out.
// ---------------------------------------------------------------------------
__global__ __launch_bounds__(256) void sortB(
    const int* __restrict__ bbase, const uint2* __restrict__ stage,
    int* __restrict__ rowstart, unsigned* __restrict__ recs) {
  __shared__ int cnt[256];
  __shared__ int scn[256];
  __shared__ unsigned dest[BUCKET_CAP];
  int t = threadIdx.x;
  int b = blockIdx.x;
  int node0 = b << 8;
  int base = bbase[b];
  int total = bbase[b + 1] - base;
  const uint2* st = stage + (size_t)b * BUCKET_CAP;

  cnt[t] = 0;
  __syncthreads();
  for (int k = t; k < total; k += 256) atomicAdd(&cnt[(int)st[k].y - node0], 1);
  __syncthreads();
  int v = cnt[t];
  scn[t] = v;
  __syncthreads();
  for (int off = 1; off < 256; off <<= 1) {
    int add = (t >= off) ? scn[t - off] : 0;
    __syncthreads();
    scn[t] += add;
    __syncthreads();
  }
  int excl = scn[t] - v;
  int n = node0 + t;
  if (n < N_NODES) rowstart[n] = base + excl;
  scn[t] = excl;     // own slot only; barrier below publishes
  cnt[t] = 0;
  __syncthreads();
  for (int k = t; k < total; k += 256) {
    uint2 e = st[k];
    int ln = (int)e.y - node0;
    int r = atomicAdd(&cnt[ln], 1);
    dest[scn[ln] + r] = e.x;
  }
  __syncthreads();
  for (int k = t; k < total; k += 256) recs[base + k] = dest[k];
}

// ---------------------------------------------------------------------------
// dense64: y[n][o] = (sum_c x[n][c]*W[o][c] + b[o]) -> e5m2 byte.
// LDS-transpose epilogue: one coalesced uint4 store per thread (was 16
// scattered byte stores).
// ---------------------------------------------------------------------------
__global__ __launch_bounds__(256, 4) void dense64(
    const float* __restrict__ x, const float* __restrict__ W,
    const float* __restrict__ b, unsigned char* __restrict__ yb) {
  __shared__ float xs[64][68];
  __shared__ float Ws[64][68];
  int t = threadIdx.x;
  int row0 = blockIdx.x * 64;
  int tx = t & 15, ty = t >> 4;

  for (int i = t; i < 4096; i += 256) Ws[i >> 6][i & 63] = W[i];
  for (int i = t; i < 4096; i += 256) {
    int r = i >> 6, gr = row0 + r;
    xs[r][i & 63] = (gr < N_NODES) ? x[gr * 64 + (i & 63)] : 0.0f;
  }
  __syncthreads();

  float acc[4][4];
#pragma unroll
  for (int j = 0; j < 4; j++) {
    float bj = b[tx + 16 * j];
#pragma unroll
    for (int i = 0; i < 4; i++) acc[i][j] = bj;
  }
#pragma unroll 2
  for (int c4 = 0; c4 < 16; c4++) {
    float4 xv[4], wv[4];
#pragma unroll
    for (int i = 0; i < 4; i++) xv[i] = *(const float4*)&xs[ty * 4 + i][c4 * 4];
#pragma unroll
    for (int j = 0; j < 4; j++) wv[j] = *(const float4*)&Ws[tx + 16 * j][c4 * 4];
#pragma unroll
    for (int i = 0; i < 4; i++)
#pragma unroll
      for (int j = 0; j < 4; j++)
        acc[i][j] += xv[i].x * wv[j].x + xv[i].y * wv[j].y +
                     xv[i].z * wv[j].z + xv[i].w * wv[j].w;
  }
  __syncthreads();
#pragma unroll
  for (int i = 0; i < 4; i++)
#pragma unroll
    for (int j = 0; j < 4; j++)
      xs[ty * 4 + i][tx + 16 * j] = acc[i][j];
  __syncthreads();
  {
    int row = t >> 2, c0 = (t & 3) * 16;
    int gr = row0 + row;
    if (gr < N_NODES) {
      unsigned w[4];
#pragma unroll
      for (int q = 0; q < 4; q++) {
        float4 vv = *(const float4*)&xs[row][c0 + 4 * q];
        w[q] = enc8(vv.x) | (enc8(vv.y) << 8) | (enc8(vv.z) << 16) | (enc8(vv.w) << 24);
      }
      *(uint4*)&yb[(size_t)gr * 64 + c0] = make_uint4(w[0], w[1], w[2], w[3]);
    }
  }
}

// ---------------------------------------------------------------------------
// update64: x[n] += silu(agg[n]@W1^T+b1)@W2^T+b2   (agg fp16 in)
// LDS-transpose epilogue: coalesced float4 read-modify-writes.
// ---------------------------------------------------------------------------
__global__ __launch_bounds__(256, 4) void update64(
    const __half* __restrict__ aggh,
    const float* __restrict__ W1, const float* __restrict__ b1,
    const float* __restrict__ W2, const float* __restrict__ b2,
    float* __restrict__ x) {
  __shared__ float as[64][68];
  __shared__ float Ws[64][68];
  int t = threadIdx.x;
  int row0 = blockIdx.x * 64;
  int tx = t & 15, ty = t >> 4;

  for (int i = t; i < 4096; i += 256) Ws[i >> 6][i & 63] = W1[i];
  for (int i = t; i < 2048; i += 256) {
    int r = i >> 5, c2 = (i & 31) * 2, gr = row0 + r;
    __half2 hv = __floats2half2_rn(0.0f, 0.0f);
    if (gr < N_NODES) hv = ((const __half2*)aggh)[gr * 32 + (i & 31)];
    as[r][c2]     = __low2float(hv);
    as[r][c2 + 1] = __high2float(hv);
  }
  __syncthreads();

  float acc[4][4];
#pragma unroll
  for (int j = 0; j < 4; j++) {
    float bj = b1[tx + 16 * j];
#pragma unroll
    for (int i = 0; i < 4; i++) acc[i][j] = bj;
  }
#pragma unroll 2
  for (int c4 = 0; c4 < 16; c4++) {
    float4 xv[4], wv[4];
#pragma unroll
    for (int i = 0; i < 4; i++) xv[i] = *(const float4*)&as[ty * 4 + i][c4 * 4];
#pragma unroll
    for (int j = 0; j < 4; j++) wv[j] = *(const float4*)&Ws[tx + 16 * j][c4 * 4];
#pragma unroll
    for (int i = 0; i < 4; i++)
#pragma unroll
      for (int j = 0; j < 4; j++)
        acc[i][j] += xv[i].x * wv[j].x + xv[i].y * wv[j].y +
                     xv[i].z * wv[j].z + xv[i].w * wv[j].w;
  }
  __syncthreads();
#pragma unroll
  for (int i = 0; i < 4; i++)
#pragma unroll
    for (int j = 0; j < 4; j++) {
      float s = acc[i][j];
      as[ty * 4 + i][tx + 16 * j] = s / (1.0f + expf(-s));
    }
  for (int i = t; i < 4096; i += 256) Ws[i >> 6][i & 63] = W2[i];
  __syncthreads();

#pragma unroll
  for (int j = 0; j < 4; j++) {
    float bj = b2[tx + 16 * j];
#pragma unroll
    for (int i = 0; i < 4; i++) acc[i][j] = bj;
  }
#pragma unroll 2
  for (int c4 = 0; c4 < 16; c4++) {
    float4 xv[4], wv[4];
#pragma unroll
    for (int i = 0; i < 4; i++) xv[i] = *(const float4*)&as[ty * 4 + i][c4 * 4];
#pragma unroll
    for (int j = 0; j < 4; j++) wv[j] = *(const float4*)&Ws[tx + 16 * j][c4 * 4];
#pragma unroll
    for (int i = 0; i < 4; i++)
#pragma unroll
      for (int j = 0; j < 4; j++)
        acc[i][j] += xv[i].x * wv[j].x + xv[i].y * wv[j].y +
                     xv[i].z * wv[j].z + xv[i].w * wv[j].w;
  }
  __syncthreads();
#pragma unroll
  for (int i = 0; i < 4; i++)
#pragma unroll
    for (int j = 0; j < 4; j++)
      as[ty * 4 + i][tx + 16 * j] = acc[i][j];
  __syncthreads();
  {
    int row = t >> 2, c0 = (t & 3) * 16;
    int gr = row0 + row;
    if (gr < N_NODES) {
      float* xp = x + (size_t)gr * 64 + c0;
#pragma unroll
      for (int q = 0; q < 4; q++) {
        float4 xv = *(float4*)(xp + 4 * q);
        float4 av = *(const float4*)&as[row][c0 + 4 * q];
        xv.x += av.x; xv.y += av.y; xv.z += av.z; xv.w += av.w;
        *(float4*)(xp + 4 * q) = xv;
      }
    }
  }
}

// ---------------------------------------------------------------------------
// CSR gather: records are wave-uniform -> force scalar path (readfirstlane
// bounds => uniform loop index => s_load records + SALU decode; vector lanes
// only do the per-channel byte loads + lerp FMAs).
// ---------------------------------------------------------------------------
__global__ __launch_bounds__(256) void gather_kernel(
    const int* __restrict__ rowstart, const unsigned* __restrict__ recs,
    const unsigned short* __restrict__ tabP8,
    const unsigned char* __restrict__ yb,
    __half* __restrict__ aggh) {
  int d = blockIdx.x * 4 + (threadIdx.x >> 6);
  int lane = threadIdx.x & 63;
  int b0 = __builtin_amdgcn_readfirstlane(rowstart[d]);
  int b1 = __builtin_amdgcn_readfirstlane(rowstart[d + 1]);
  float acc = 0.0f;
  int j = b0;
  for (; j + 4 <= b1; j += 4) {
    unsigned u0 = recs[j];        // uniform index -> scalar load
    unsigned u1 = recs[j + 1];
    unsigned u2 = recs[j + 2];
    unsigned u3 = recs[j + 3];
    unsigned y0 = yb[((u0 >> 15) << 6) + lane];
    unsigned y1 = yb[((u1 >> 15) << 6) + lane];
    unsigned y2 = yb[((u2 >> 15) << 6) + lane];
    unsigned y3 = yb[((u3 >> 15) << 6) + lane];
    unsigned p0 = tabP8[(((u0 & 32767u) >> 3) << 6) + lane];
    unsigned p1 = tabP8[(((u1 & 32767u) >> 3) << 6) + lane];
    unsigned p2 = tabP8[(((u2 & 32767u) >> 3) << 6) + lane];
    unsigned p3 = tabP8[(((u3 & 32767u) >> 3) << 6) + lane];
    float fr0 = (float)(u0 & 7u) * 0.125f;
    float fr1 = (float)(u1 & 7u) * 0.125f;
    float fr2 = (float)(u2 & 7u) * 0.125f;
    float fr3 = (float)(u3 & 7u) * 0.125f;
    float a0 = dec8(p0 & 0xffu), g0 = dec8(p0 >> 8);
    float a1 = dec8(p1 & 0xffu), g1 = dec8(p1 >> 8);
    float a2 = dec8(p2 & 0xffu), g2 = dec8(p2 >> 8);
    float a3 = dec8(p3 & 0xffu), g3 = dec8(p3 >> 8);
    acc += dec8(y0) * (a0 + (g0 - a0) * fr0);
    acc += dec8(y1) * (a1 + (g1 - a1) * fr1);
    acc += dec8(y2) * (a2 + (g2 - a2) * fr2);
    acc += dec8(y3) * (a3 + (g3 - a3) * fr3);
  }
  for (; j < b1; j++) {
    unsigned u = recs[j];
    unsigned yv = yb[((u >> 15) << 6) + lane];
    unsigned p = tabP8[(((u & 32767u) >> 3) << 6) + lane];
    float fr = (float)(u & 7u) * 0.125f;
    float a = dec8(p & 0xffu), g = dec8(p >> 8);
    acc += dec8(yv) * (a + (g - a) * fr);
  }
  aggh[d * 64 + lane] = __float2half(acc);
}

// ---------------------------------------------------------------------------
__global__ __launch_bounds__(256) void pool_kernel(
    const float* __restrict__ x, const int* __restrict__ batch,
    float* __restrict__ pooled, float* __restrict__ counts) {
  int wid = (blockIdx.x * 256 + threadIdx.x) >> 6;
  int lane = threadIdx.x & 63;
  int n0 = wid * 64;
  if (n0 >= N_NODES) return;
  int n1 = n0 + 64; if (n1 > N_NODES) n1 = N_NODES;
  int curg = batch[n0];
  float acc = 0.0f, cnt = 0.0f;
  for (int n = n0; n < n1; n++) {
    int g = batch[n];
    if (g != curg) {
      unsafeAtomicAdd(&pooled[curg * 64 + lane], acc);
      if (lane == 0) unsafeAtomicAdd(&counts[curg], cnt);
      curg = g; acc = 0.0f; cnt = 0.0f;
    }
    acc += x[n * 64 + lane];
    cnt += 1.0f;
  }
  unsafeAtomicAdd(&pooled[curg * 64 + lane], acc);
  if (lane == 0) unsafeAtomicAdd(&counts[curg], cnt);
}

// ---------------------------------------------------------------------------
__global__ __launch_bounds__(256) void gate_kernel(
    const float* __restrict__ pooled, const float* __restrict__ counts,
    const float* __restrict__ mlip,
    const float* __restrict__ gW1, const float* __restrict__ gb1,
    const float* __restrict__ gW2, const float* __restrict__ gb2,
    const float* __restrict__ gW3, const float* __restrict__ gb3,
    float* __restrict__ out) {
  __shared__ float ins[4][GATE_IN];
  __shared__ float h1s[4][G1_DIM];
  __shared__ float h2s[4][G2_DIM];
  __shared__ float lg[4][N_EXPERTS];
  int wv = threadIdx.x >> 6, lane = threadIdx.x & 63;
  int g = blockIdx.x * 4 + wv;

  float cnt = counts[g];
  if (cnt < 1.0f) cnt = 1.0f;
  ins[wv][lane] = pooled[g * 64 + lane] / cnt;
  if (lane < N_EXPERTS) ins[wv][64 + lane] = mlip[g * N_EXPERTS + lane];
  __syncthreads();

  {
    float s = gb1[lane];
    for (int c = 0; c < GATE_IN; c++) s += ins[wv][c] * gW1[lane * GATE_IN + c];
    h1s[wv][lane] = fmaxf(s, 0.0f);
  }
  __syncthreads();
  if (lane < G2_DIM) {
    float s = gb2[lane];
    for (int c = 0; c < G1_DIM; c++) s += h1s[wv][c] * gW2[lane * G1_DIM + c];
    h2s[wv][lane] = fmaxf(s, 0.0f);
  }
  __syncthreads();
  if (lane < N_EXPERTS) {
    float s = gb3[lane];
    for (int c = 0; c < G2_DIM; c++) s += h2s[wv][c] * gW3[lane * G2_DIM + c];
    lg[wv][lane] = s;
  }
  __syncthreads();
  if (lane < N_EXPERTS) {
    float m = -1e30f;
    for (int j = 0; j < N_EXPERTS; j++) m = fmaxf(m, lg[wv][j]);
    float den = 0.0f;
    for (int j = 0; j < N_EXPERTS; j++) den += expf(lg[wv][j] - m);
    float wgt = expf(lg[wv][lane] - m) / den;
    out[g * 8 + lane] = lg[wv][lane];
    out[N_GRAPHS * 8 + g * 8 + lane] = wgt;
    if (lane == 0) {
      float p = 0.0f;
      for (int j = 0; j < N_EXPERTS; j++)
        p += mlip[g * 8 + j] * expf(lg[wv][j] - m) / den;
      out[N_GRAPHS * 16 + g] = p;
    }
  }
}

// ---------------------------------------------------------------------------
extern "C" void kernel_launch(void* const* d_in, const int* in_sizes, int n_in,
                              void* d_out, int out_size, void* d_ws, size_t ws_size,
                              hipStream_t stream) {
  const int*   z     = (const int*)  d_in[0];
  const int*   ei    = (const int*)  d_in[1];
  const float* ew    = (const float*)d_in[2];
  const int*   batch = (const int*)  d_in[3];
  const float* mlip  = (const float*)d_in[4];
  const float* emb   = (const float*)d_in[5];
  const float* fW1   = (const float*)d_in[6];
  const float* fb1   = (const float*)d_in[7];
  const float* fW2   = (const float*)d_in[8];
  const float* fb2   = (const float*)d_in[9];
  const float* dW    = (const float*)d_in[10];
  const float* db    = (const float*)d_in[11];
  const float* uW1   = (const float*)d_in[12];
  const float* ub1   = (const float*)d_in[13];
  const float* uW2   = (const float*)d_in[14];
  const float* ub2   = (const float*)d_in[15];
  const float* gW1   = (const float*)d_in[16];
  const float* gb1   = (const float*)d_in[17];
  const float* gW2   = (const float*)d_in[18];
  const float* gb2   = (const float*)d_in[19];
  const float* gW3   = (const float*)d_in[20];
  const float* gb3   = (const float*)d_in[21];

  const int* src = ei;
  const int* dst = ei + N_EDGES;

  float* ws = (float*)d_ws;
  float*          x        = ws;                               // [0, 6.4M)
  unsigned char*  yb       = (unsigned char*)(ws + 6400000);   // 6.4MB
  __half*         aggh     = (__half*)(ws + 8000000);          // 12.8MB
  float*          tab      = ws + 11200000;                    // 786,624 f
  unsigned short* tabP8    = (unsigned short*)(ws + 11986624); // 393,216 f
  float*          pooled   = ws + 12379840;                    // 32,768
  float*          counts   = ws + 12412608;                    // 512
  int*            rowstart = (int*)(ws + 12413120);            // 100,001
  unsigned*       recs     = (unsigned*)(ws + 12513121);       // 1,250,000
  int*            gcnt     = (int*)(ws + 13763121);            // 391
  int*            bbase    = (int*)(ws + 13763512);            // 392
  uint2*          stage    = (uint2*)(ws + 13763904);          // 391*4608*8B -> end 69.5 MB

  // --- CSR build (once per launch) ---
  hipMemsetAsync(gcnt, 0, N_BUCKET * sizeof(int), stream);
  partitionA<<<(N_EDGES + CHUNK_A - 1) / CHUNK_A, 256, 0, stream>>>(
      src, dst, ew, gcnt, stage);
  bscan_kernel<<<1, 512, 0, stream>>>(gcnt, bbase, rowstart);
  sortB<<<N_BUCKET, 256, 0, stream>>>(bbase, stage, rowstart, recs);

  build_tab<<<N_LAYERS * 1025, 256, 0, stream>>>(fW1, fb1, fW2, fb2, tab);
  pack_tab8<<<(N_LAYERS * K_TAB * 64) / 256, 256, 0, stream>>>(tab, tabP8);
  embed_kernel<<<(N_NODES * HID + 255) / 256, 256, 0, stream>>>(z, emb, x);

  for (int i = 0; i < N_LAYERS; i++) {
    dense64<<<(N_NODES + 63) / 64, 256, 0, stream>>>(x, dW + i * 4096, db + i * 64, yb);
    gather_kernel<<<(N_NODES + 3) / 4, 256, 0, stream>>>(
        rowstart, recs, tabP8 + i * K_TAB * 64, yb, aggh);
    update64<<<(N_NODES + 63) / 64, 256, 0, stream>>>(aggh, uW1 + i * 4096, ub1 + i * 64,
                                                      uW2 + i * 4096, ub2 + i * 64, x);
  }

  hipMemsetAsync(pooled, 0, (size_t)(N_GRAPHS * HID + N_GRAPHS) * sizeof(float), stream);
  pool_kernel<<<(N_NODES / 64 + 1 + 3) / 4, 256, 0, stream>>>(x, batch, pooled, counts);
  gate_kernel<<<N_GRAPHS / 4, 256, 0, stream>>>(pooled, counts, mlip,
                                                gW1, gb1, gW2, gb2, gW3, gb3,
                                                (float*)d_out);
}

// Round 7
// 419.362 us; speedup vs baseline: 2.5803x; 1.3131x over previous
//
#include <hip/hip_runtime.h>
#include <hip/hip_fp16.h>
#include <math.h>

#define N_NODES   100000
#define N_EDGES   1250000
#define HID       64
#define N_RBF     32
#define N_GRAPHS  512
#define N_EXPERTS 8
#define N_LAYERS  3
#define CUTOFF    6.0f
#define GATE_IN   72
#define G1_DIM    64
#define G2_DIM    32
#define K_TAB     4096   // lerp intervals
#define N_BUCKET  391    // 256-node buckets
#define BUCKET_CAP 4608  // mean 3200, sigma 56.5 -> +25 sigma
#define CHUNK_A   8192

typedef short short8 __attribute__((ext_vector_type(8)));
typedef float float4v __attribute__((ext_vector_type(4)));

// e5m2 encode: fp16 bits, round-half-up in magnitude, keep high byte.
__device__ __forceinline__ unsigned enc8(float v) {
  unsigned short u = __half_as_ushort(__float2half(v));
  return (unsigned)((unsigned short)(u + 0x80u) >> 8);
}
__device__ __forceinline__ float dec8(unsigned b) {
  return __half2float(__ushort_as_half((unsigned short)(b << 8)));
}
// bf16 round-to-nearest-even
__device__ __forceinline__ unsigned short bf16(float f) {
  unsigned u = __float_as_uint(f);
  u += 0x7fffu + ((u >> 16) & 1u);
  return (unsigned short)(u >> 16);
}

// ---------------------------------------------------------------------------
// Filter table (fp32): f_i(w) = silu(rbf(w)@fW1^T+fb1)@fW2^T+fb2
// ---------------------------------------------------------------------------
__global__ __launch_bounds__(256) void build_tab(
    const float* __restrict__ fW1, const float* __restrict__ fb1,
    const float* __restrict__ fW2, const float* __restrict__ fb2,
    float* __restrict__ tab) {
  __shared__ float W1s[64][33];
  __shared__ float W2s[64][65];
  __shared__ float rbfs[4][32];
  __shared__ float h1s[4][64];
  int t = threadIdx.x;
  int wv = t >> 6, lane = t & 63;
  int layer = blockIdx.x / 1025;
  int k = (blockIdx.x % 1025) * 4 + wv;

  for (int i = t; i < 64 * 32; i += 256) W1s[i >> 5][i & 31] = fW1[layer * 2048 + i];
  for (int i = t; i < 64 * 64; i += 256) W2s[i >> 6][i & 63] = fW2[layer * 4096 + i];

  float w = (CUTOFF / (float)K_TAB) * (float)k;
  const float delta = CUTOFF / (float)(N_RBF - 1);
  const float coeff = -0.5f / (delta * delta);
  __syncthreads();

  if (lane < N_RBF) {
    float d = w - delta * (float)lane;
    rbfs[wv][lane] = expf(coeff * d * d);
  }
  __syncthreads();

  float s = fb1[layer * HID + lane];
#pragma unroll
  for (int j = 0; j < N_RBF; j++) s += rbfs[wv][j] * W1s[lane][j];
  h1s[wv][lane] = s / (1.0f + expf(-s));
  __syncthreads();

  float f = fb2[layer * HID + lane];
#pragma unroll
  for (int c = 0; c < HID; c++) f += h1s[wv][c] * W2s[lane][c];
  if (k <= K_TAB) tab[(layer * (K_TAB + 1) + k) * HID + lane] = f;
}

// Pack lerp pairs as 2x e5m2 bytes: tabP8[layer][k][lane] = (f[k], f[k+1])
__global__ __launch_bounds__(256) void pack_tab8(
    const float* __restrict__ tab, unsigned short* __restrict__ tabP8) {
  int i = blockIdx.x * 256 + threadIdx.x;     // 3*4096*64
  if (i >= N_LAYERS * K_TAB * 64) return;
  int layer = i / (K_TAB * 64);
  int r = i - layer * (K_TAB * 64);
  const float* base = tab + layer * (K_TAB + 1) * 64;
  tabP8[i] = (unsigned short)(enc8(base[r]) | (enc8(base[r + 64]) << 8));
}

// Convert SchNet weights to bf16 (once per launch).
__global__ __launch_bounds__(256) void conv_w(
    const float* __restrict__ dW, const float* __restrict__ uW1,
    const float* __restrict__ uW2, unsigned short* __restrict__ dWh,
    unsigned short* __restrict__ uW1h, unsigned short* __restrict__ uW2h) {
  int i = blockIdx.x * 256 + threadIdx.x;
  if (i < N_LAYERS * 4096) {
    dWh[i]  = bf16(dW[i]);
    uW1h[i] = bf16(uW1[i]);
    uW2h[i] = bf16(uW2[i]);
  }
}

// ---------------------------------------------------------------------------
__global__ __launch_bounds__(256) void embed_kernel(
    const int* __restrict__ z, const float* __restrict__ emb,
    float* __restrict__ x) {
  int i = blockIdx.x * 256 + threadIdx.x;
  if (i < N_NODES * HID) {
    int n = i >> 6, h = i & 63;
    x[i] = emb[z[n] * HID + h];
  }
}

// ---------------------------------------------------------------------------
// Phase A: partition edges into 391 fixed-capacity buckets (256 nodes each).
// ---------------------------------------------------------------------------
__global__ __launch_bounds__(256) void partitionA(
    const int* __restrict__ src, const int* __restrict__ dst,
    const float* __restrict__ ew, int* __restrict__ gcnt,
    uint2* __restrict__ stage) {
  __shared__ int hist[N_BUCKET];
  __shared__ int base[N_BUCKET];
  int t = threadIdx.x;
  int e0 = blockIdx.x * CHUNK_A;
  int e1 = e0 + CHUNK_A; if (e1 > N_EDGES) e1 = N_EDGES;

  for (int i = t; i < N_BUCKET; i += 256) hist[i] = 0;
  __syncthreads();
  for (int e = e0 + t; e < e1; e += 256)
    atomicAdd(&hist[dst[e] >> 8], 1);
  __syncthreads();
  for (int i = t; i < N_BUCKET; i += 256) {
    int c = hist[i];
    base[i] = c ? atomicAdd(&gcnt[i], c) : 0;
    hist[i] = 0;
  }
  __syncthreads();
  for (int e = e0 + t; e < e1; e += 256) {
    int d = dst[e];
    int b = d >> 8;
    int r = base[b] + atomicAdd(&hist[b], 1);
    if (r < BUCKET_CAP) {
      float uq = ew[e] * ((float)K_TAB * 8.0f / CUTOFF);
      int wq = (int)(uq + 0.5f);
      if (wq > 32767) wq = 32767;
      stage[(size_t)b * BUCKET_CAP + r] =
          make_uint2(((unsigned)src[e] << 15) | (unsigned)wq, (unsigned)d);
    }
  }
}

// Scan bucket counts -> bucket bases; also rowstart[N_NODES].
__global__ __launch_bounds__(512) void bscan_kernel(
    const int* __restrict__ gcnt, int* __restrict__ bbase,
    int* __restrict__ rowstart) {
  __shared__ int sh[512];
  int t = threadIdx.x;
  int v = 0;
  if (t < N_BUCKET) {
    v = gcnt[t];
    if (v > BUCKET_CAP) v = BUCKET_CAP;
  }
  sh[t] = v;
  __syncthreads();
  for (int off = 1; off < 512; off <<= 1) {
    int add = (t >= off) ? sh[t - off] : 0;
    __syncthreads();
    sh[t] += add;
    __syncthreads();
  }
  if (t < N_BUCKET) bbase[t] = sh[t] - v;
  if (t == N_BUCKET - 1) {
    bbase[N_BUCKET] = sh[t];
    rowstart[N_NODES] = sh[t];
  }
}

// ---------------------------------------------------------------------------
// Phase B: one block per bucket; LDS counting sort -> CSR order + rowstart.
// ---------------------------------------------------------------------------
__global__ __launch_bounds__(256) void sortB(
    const int* __restrict__ bbase, const uint2* __restrict__ stage,
    int* __restrict__ rowstart, unsigned* __restrict__ recs) {
  __shared__ int cnt[256];
  __shared__ int scn[256];
  __shared__ unsigned dest[BUCKET_CAP];
  int t = threadIdx.x;
  int b = blockIdx.x;
  int node0 = b << 8;
  int base = bbase[b];
  int total = bbase[b + 1] - base;
  const uint2* st = stage + (size_t)b * BUCKET_CAP;

  cnt[t] = 0;
  __syncthreads();
  for (int k = t; k < total; k += 256) atomicAdd(&cnt[(int)st[k].y - node0], 1);
  __syncthreads();
  int v = cnt[t];
  scn[t] = v;
  __syncthreads();
  for (int off = 1; off < 256; off <<= 1) {
    int add = (t >= off) ? scn[t - off] : 0;
    __syncthreads();
    scn[t] += add;
    __syncthreads();
  }
  int excl = scn[t] - v;
  int n = node0 + t;
  if (n < N_NODES) rowstart[n] = base + excl;
  scn[t] = excl;
  cnt[t] = 0;
  __syncthreads();
  for (int k = t; k < total; k += 256) {
    uint2 e = st[k];
    int ln = (int)e.y - node0;
    int r = atomicAdd(&cnt[ln], 1);
    dest[scn[ln] + r] = e.x;
  }
  __syncthreads();
  for (int k = t; k < total; k += 256) recs[base + k] = dest[k];
}

// ---------------------------------------------------------------------------
// dense64 (MFMA): y[n] = x[n] @ W^T + b  -> e5m2 bytes.
// ---------------------------------------------------------------------------
__global__ __launch_bounds__(256, 4) void dense64(
    const float* __restrict__ x, const unsigned short* __restrict__ Wh,
    const float* __restrict__ b, unsigned char* __restrict__ yb) {
  __shared__ __align__(16) unsigned char smem[18432];
  short* As = (short*)smem;            // [64][72] bf16
  short* Bs = As + 64 * 72;            // [64][72] bf16
  float* Es = (float*)smem;            // [64][68] epilogue (reuse)
  int t = threadIdx.x;
  int row0 = blockIdx.x * 64;

#pragma unroll
  for (int it = 0; it < 4; it++) {
    int i = it * 1024 + t * 4;
    int r = i >> 6, c = i & 63;
    int gr = row0 + r;
    float4 v = make_float4(0.f, 0.f, 0.f, 0.f);
    if (gr < N_NODES) v = *(const float4*)&x[(size_t)gr * 64 + c];
    short4 h;
    h.x = (short)bf16(v.x); h.y = (short)bf16(v.y);
    h.z = (short)bf16(v.z); h.w = (short)bf16(v.w);
    *(short4*)&As[r * 72 + c] = h;
  }
#pragma unroll
  for (int it = 0; it < 2; it++) {
    int i = it * 2048 + t * 8;
    int r = i >> 6, c = i & 63;
    *(uint4*)&Bs[r * 72 + c] = *(const uint4*)&Wh[i];
  }
  __syncthreads();

  int lane = t & 63, wv = t >> 6;
  int m = lane & 15, quad = lane >> 4;
  const short* arow = As + (wv * 16 + m) * 72 + quad * 8;
  short8 a0 = *(const short8*)arow;
  short8 a1 = *(const short8*)(arow + 32);
  float4v acc[4];
#pragma unroll
  for (int ct = 0; ct < 4; ct++) {
    const short* brow = Bs + (ct * 16 + m) * 72 + quad * 8;
    short8 bf0 = *(const short8*)brow;
    short8 bf1 = *(const short8*)(brow + 32);
    float bj = b[ct * 16 + m];
    float4v c = {bj, bj, bj, bj};
    c = __builtin_amdgcn_mfma_f32_16x16x32_bf16(a0, bf0, c, 0, 0, 0);
    c = __builtin_amdgcn_mfma_f32_16x16x32_bf16(a1, bf1, c, 0, 0, 0);
    acc[ct] = c;
  }
  __syncthreads();
#pragma unroll
  for (int ct = 0; ct < 4; ct++)
#pragma unroll
    for (int r = 0; r < 4; r++)
      Es[(wv * 16 + quad * 4 + r) * 68 + ct * 16 + m] = acc[ct][r];
  __syncthreads();
  {
    int row = t >> 2, c0 = (t & 3) * 16;
    int gr = row0 + row;
    if (gr < N_NODES) {
      unsigned w[4];
#pragma unroll
      for (int q = 0; q < 4; q++) {
        const float* p = &Es[row * 68 + c0 + 4 * q];
        w[q] = enc8(p[0]) | (enc8(p[1]) << 8) | (enc8(p[2]) << 16) | (enc8(p[3]) << 24);
      }
      *(uint4*)&yb[(size_t)gr * 64 + c0] = make_uint4(w[0], w[1], w[2], w[3]);
    }
  }
}

// ---------------------------------------------------------------------------
// update64 (MFMA): x[n] += silu(agg[n]@W1^T+b1)@W2^T+b2.  agg bf16 in.
// ---------------------------------------------------------------------------
__global__ __launch_bounds__(256, 4) void update64(
    const unsigned short* __restrict__ aggb,
    const unsigned short* __restrict__ W1h, const float* __restrict__ b1,
    const unsigned short* __restrict__ W2h, const float* __restrict__ b2,
    float* __restrict__ x) {
  __shared__ __align__(16) unsigned char smem[18432];
  short* As = (short*)smem;            // [64][72] bf16 (agg, then h)
  short* Bs = As + 64 * 72;            // [64][72] bf16 (W1, then W2)
  float* Es = (float*)smem;            // [64][68] epilogue (reuse)
  int t = threadIdx.x;
  int row0 = blockIdx.x * 64;
  int lane = t & 63, wv = t >> 6;
  int m = lane & 15, quad = lane >> 4;

#pragma unroll
  for (int it = 0; it < 2; it++) {
    int i = it * 2048 + t * 8;
    int r = i >> 6, c = i & 63;
    int gr = row0 + r;
    uint4 v = make_uint4(0u, 0u, 0u, 0u);
    if (gr < N_NODES) v = *(const uint4*)&aggb[(size_t)gr * 64 + c];
    *(uint4*)&As[r * 72 + c] = v;
    *(uint4*)&Bs[r * 72 + c] = *(const uint4*)&W1h[i];
  }
  __syncthreads();

  const short* arow = As + (wv * 16 + m) * 72 + quad * 8;
  float4v acc[4];
  {
    short8 a0 = *(const short8*)arow;
    short8 a1 = *(const short8*)(arow + 32);
#pragma unroll
    for (int ct = 0; ct < 4; ct++) {
      const short* brow = Bs + (ct * 16 + m) * 72 + quad * 8;
      short8 bf0 = *(const short8*)brow;
      short8 bf1 = *(const short8*)(brow + 32);
      float bj = b1[ct * 16 + m];
      float4v c = {bj, bj, bj, bj};
      c = __builtin_amdgcn_mfma_f32_16x16x32_bf16(a0, bf0, c, 0, 0, 0);
      c = __builtin_amdgcn_mfma_f32_16x16x32_bf16(a1, bf1, c, 0, 0, 0);
      acc[ct] = c;
    }
  }
  __syncthreads();
#pragma unroll
  for (int ct = 0; ct < 4; ct++)
#pragma unroll
    for (int r = 0; r < 4; r++) {
      float s = acc[ct][r];
      float h = s / (1.0f + expf(-s));
      As[(wv * 16 + quad * 4 + r) * 72 + ct * 16 + m] = (short)bf16(h);
    }
#pragma unroll
  for (int it = 0; it < 2; it++) {
    int i = it * 2048 + t * 8;
    int r = i >> 6, c = i & 63;
    *(uint4*)&Bs[r * 72 + c] = *(const uint4*)&W2h[i];
  }
  __syncthreads();

  {
    short8 a0 = *(const short8*)arow;
    short8 a1 = *(const short8*)(arow + 32);
#pragma unroll
    for (int ct = 0; ct < 4; ct++) {
      const short* brow = Bs + (ct * 16 + m) * 72 + quad * 8;
      short8 bf0 = *(const short8*)brow;
      short8 bf1 = *(const short8*)(brow + 32);
      float bj = b2[ct * 16 + m];
      float4v c = {bj, bj, bj, bj};
      c = __builtin_amdgcn_mfma_f32_16x16x32_bf16(a0, bf0, c, 0, 0, 0);
      c = __builtin_amdgcn_mfma_f32_16x16x32_bf16(a1, bf1, c, 0, 0, 0);
      acc[ct] = c;
    }
  }
  __syncthreads();
#pragma unroll
  for (int ct = 0; ct < 4; ct++)
#pragma unroll
    for (int r = 0; r < 4; r++)
      Es[(wv * 16 + quad * 4 + r) * 68 + ct * 16 + m] = acc[ct][r];
  __syncthreads();
  {
    int row = t >> 2, c0 = (t & 3) * 16;
    int gr = row0 + row;
    if (gr < N_NODES) {
      float* xp = x + (size_t)gr * 64 + c0;
#pragma unroll
      for (int q = 0; q < 4; q++) {
        float4 xv = *(float4*)(xp + 4 * q);
        float4 av = *(const float4*)&Es[row * 68 + c0 + 4 * q];
        xv.x += av.x; xv.y += av.y; xv.z += av.z; xv.w += av.w;
        *(float4*)(xp + 4 * q) = xv;
      }
    }
  }
}

// ---------------------------------------------------------------------------
// CSR gather: scalarized records, e5m2 payloads, bf16 output.
// ---------------------------------------------------------------------------
__global__ __launch_bounds__(256) void gather_kernel(
    const int* __restrict__ rowstart, const unsigned* __restrict__ recs,
    const unsigned short* __restrict__ tabP8,
    const unsigned char* __restrict__ yb,
    unsigned short* __restrict__ aggb) {
  int d = blockIdx.x * 4 + (threadIdx.x >> 6);
  int lane = threadIdx.x & 63;
  int b0 = __builtin_amdgcn_readfirstlane(rowstart[d]);
  int b1 = __builtin_amdgcn_readfirstlane(rowstart[d + 1]);
  float acc = 0.0f;
  int j = b0;
  for (; j + 4 <= b1; j += 4) {
    unsigned u0 = recs[j];
    unsigned u1 = recs[j + 1];
    unsigned u2 = recs[j + 2];
    unsigned u3 = recs[j + 3];
    unsigned y0 = yb[((u0 >> 15) << 6) + lane];
    unsigned y1 = yb[((u1 >> 15) << 6) + lane];
    unsigned y2 = yb[((u2 >> 15) << 6) + lane];
    unsigned y3 = yb[((u3 >> 15) << 6) + lane];
    unsigned p0 = tabP8[(((u0 & 32767u) >> 3) << 6) + lane];
    unsigned p1 = tabP8[(((u1 & 32767u) >> 3) << 6) + lane];
    unsigned p2 = tabP8[(((u2 & 32767u) >> 3) << 6) + lane];
    unsigned p3 = tabP8[(((u3 & 32767u) >> 3) << 6) + lane];
    float fr0 = (float)(u0 & 7u) * 0.125f;
    float fr1 = (float)(u1 & 7u) * 0.125f;
    float fr2 = (float)(u2 & 7u) * 0.125f;
    float fr3 = (float)(u3 & 7u) * 0.125f;
    float a0 = dec8(p0 & 0xffu), g0 = dec8(p0 >> 8);
    float a1 = dec8(p1 & 0xffu), g1 = dec8(p1 >> 8);
    float a2 = dec8(p2 & 0xffu), g2 = dec8(p2 >> 8);
    float a3 = dec8(p3 & 0xffu), g3 = dec8(p3 >> 8);
    acc += dec8(y0) * (a0 + (g0 - a0) * fr0);
    acc += dec8(y1) * (a1 + (g1 - a1) * fr1);
    acc += dec8(y2) * (a2 + (g2 - a2) * fr2);
    acc += dec8(y3) * (a3 + (g3 - a3) * fr3);
  }
  for (; j < b1; j++) {
    unsigned u = recs[j];
    unsigned yv = yb[((u >> 15) << 6) + lane];
    unsigned p = tabP8[(((u & 32767u) >> 3) << 6) + lane];
    float fr = (float)(u & 7u) * 0.125f;
    float a = dec8(p & 0xffu), g = dec8(p >> 8);
    acc += dec8(yv) * (a + (g - a) * fr);
  }
  aggb[(size_t)d * 64 + lane] = bf16(acc);
}

// ---------------------------------------------------------------------------
__global__ __launch_bounds__(256) void pool_kernel(
    const float* __restrict__ x, const int* __restrict__ batch,
    float* __restrict__ pooled, float* __restrict__ counts) {
  int wid = (blockIdx.x * 256 + threadIdx.x) >> 6;
  int lane = threadIdx.x & 63;
  int n0 = wid * 64;
  if (n0 >= N_NODES) return;
  int n1 = n0 + 64; if (n1 > N_NODES) n1 = N_NODES;
  int curg = batch[n0];
  float acc = 0.0f, cnt = 0.0f;
  for (int n = n0; n < n1; n++) {
    int g = batch[n];
    if (g != curg) {
      unsafeAtomicAdd(&pooled[curg * 64 + lane], acc);
      if (lane == 0) unsafeAtomicAdd(&counts[curg], cnt);
      curg = g; acc = 0.0f; cnt = 0.0f;
    }
    acc += x[n * 64 + lane];
    cnt += 1.0f;
  }
  unsafeAtomicAdd(&pooled[curg * 64 + lane], acc);
  if (lane == 0) unsafeAtomicAdd(&counts[curg], cnt);
}

// ---------------------------------------------------------------------------
__global__ __launch_bounds__(256) void gate_kernel(
    const float* __restrict__ pooled, const float* __restrict__ counts,
    const float* __restrict__ mlip,
    const float* __restrict__ gW1, const float* __restrict__ gb1,
    const float* __restrict__ gW2, const float* __restrict__ gb2,
    const float* __restrict__ gW3, const float* __restrict__ gb3,
    float* __restrict__ out) {
  __shared__ float ins[4][GATE_IN];
  __shared__ float h1s[4][G1_DIM];
  __shared__ float h2s[4][G2_DIM];
  __shared__ float lg[4][N_EXPERTS];
  int wv = threadIdx.x >> 6, lane = threadIdx.x & 63;
  int g = blockIdx.x * 4 + wv;

  float cnt = counts[g];
  if (cnt < 1.0f) cnt = 1.0f;
  ins[wv][lane] = pooled[g * 64 + lane] / cnt;
  if (lane < N_EXPERTS) ins[wv][64 + lane] = mlip[g * N_EXPERTS + lane];
  __syncthreads();

  {
    float s = gb1[lane];
    for (int c = 0; c < GATE_IN; c++) s += ins[wv][c] * gW1[lane * GATE_IN + c];
    h1s[wv][lane] = fmaxf(s, 0.0f);
  }
  __syncthreads();
  if (lane < G2_DIM) {
    float s = gb2[lane];
    for (int c = 0; c < G1_DIM; c++) s += h1s[wv][c] * gW2[lane * G1_DIM + c];
    h2s[wv][lane] = fmaxf(s, 0.0f);
  }
  __syncthreads();
  if (lane < N_EXPERTS) {
    float s = gb3[lane];
    for (int c = 0; c < G2_DIM; c++) s += h2s[wv][c] * gW3[lane * G2_DIM + c];
    lg[wv][lane] = s;
  }
  __syncthreads();
  if (lane < N_EXPERTS) {
    float m = -1e30f;
    for (int j = 0; j < N_EXPERTS; j++) m = fmaxf(m, lg[wv][j]);
    float den = 0.0f;
    for (int j = 0; j < N_EXPERTS; j++) den += expf(lg[wv][j] - m);
    float wgt = expf(lg[wv][lane] - m) / den;
    out[g * 8 + lane] = lg[wv][lane];
    out[N_GRAPHS * 8 + g * 8 + lane] = wgt;
    if (lane == 0) {
      float p = 0.0f;
      for (int j = 0; j < N_EXPERTS; j++)
        p += mlip[g * 8 + j] * expf(lg[wv][j] - m) / den;
      out[N_GRAPHS * 16 + g] = p;
    }
  }
}

// ---------------------------------------------------------------------------
extern "C" void kernel_launch(void* const* d_in, const int* in_sizes, int n_in,
                              void* d_out, int out_size, void* d_ws, size_t ws_size,
                              hipStream_t stream) {
  const int*   z     = (const int*)  d_in[0];
  const int*   ei    = (const int*)  d_in[1];
  const float* ew    = (const float*)d_in[2];
  const int*   batch = (const int*)  d_in[3];
  const float* mlip  = (const float*)d_in[4];
  const float* emb   = (const float*)d_in[5];
  const float* fW1   = (const float*)d_in[6];
  const float* fb1   = (const float*)d_in[7];
  const float* fW2   = (const float*)d_in[8];
  const float* fb2   = (const float*)d_in[9];
  const float* dW    = (const float*)d_in[10];
  const float* db    = (const float*)d_in[11];
  const float* uW1   = (const float*)d_in[12];
  const float* ub1   = (const float*)d_in[13];
  const float* uW2   = (const float*)d_in[14];
  const float* ub2   = (const float*)d_in[15];
  const float* gW1   = (const float*)d_in[16];
  const float* gb1   = (const float*)d_in[17];
  const float* gW2   = (const float*)d_in[18];
  const float* gb2   = (const float*)d_in[19];
  const float* gW3   = (const float*)d_in[20];
  const float* gb3   = (const float*)d_in[21];

  const int* src = ei;
  const int* dst = ei + N_EDGES;

  float* ws = (float*)d_ws;
  float*          x        = ws;                               // [0, 6.4M)
  unsigned char*  yb       = (unsigned char*)(ws + 6400000);   // 6.4MB
  unsigned short* aggb     = (unsigned short*)(ws + 8000000);  // 12.8MB bf16
  float*          tab      = ws + 11200000;                    // 786,624 f
  unsigned short* tabP8    = (unsigned short*)(ws + 11986624); // 393,216 f
  float*          pooled   = ws + 12379840;                    // 32,768
  float*          counts   = ws + 12412608;                    // 512
  int*            rowstart = (int*)(ws + 12413120);            // 100,001
  unsigned*       recs     = (unsigned*)(ws + 12513121);       // 1,250,000
  int*            gcnt     = (int*)(ws + 13763121);            // 391
  int*            bbase    = (int*)(ws + 13763512);            // 392
  uint2*          stage    = (uint2*)(ws + 13763904);          // 391*4608*8B
  unsigned short* dWh      = (unsigned short*)(ws + 17367360); // 12288 bf16
  unsigned short* uW1h     = dWh + N_LAYERS * 4096;
  unsigned short* uW2h     = uW1h + N_LAYERS * 4096;           // end ~69.6 MB

  // --- CSR build (once per launch) ---
  hipMemsetAsync(gcnt, 0, N_BUCKET * sizeof(int), stream);
  partitionA<<<(N_EDGES + CHUNK_A - 1) / CHUNK_A, 256, 0, stream>>>(
      src, dst, ew, gcnt, stage);
  bscan_kernel<<<1, 512, 0, stream>>>(gcnt, bbase, rowstart);
  sortB<<<N_BUCKET, 256, 0, stream>>>(bbase, stage, rowstart, recs);

  build_tab<<<N_LAYERS * 1025, 256, 0, stream>>>(fW1, fb1, fW2, fb2, tab);
  pack_tab8<<<(N_LAYERS * K_TAB * 64) / 256, 256, 0, stream>>>(tab, tabP8);
  conv_w<<<(N_LAYERS * 4096 + 255) / 256, 256, 0, stream>>>(dW, uW1, uW2, dWh, uW1h, uW2h);
  embed_kernel<<<(N_NODES * HID + 255) / 256, 256, 0, stream>>>(z, emb, x);

  for (int i = 0; i < N_LAYERS; i++) {
    dense64<<<(N_NODES + 63) / 64, 256, 0, stream>>>(x, dWh + i * 4096, db + i * 64, yb);
    gather_kernel<<<(N_NODES + 3) / 4, 256, 0, stream>>>(
        rowstart, recs, tabP8 + i * K_TAB * 64, yb, aggb);
    update64<<<(N_NODES + 63) / 64, 256, 0, stream>>>(aggb, uW1h + i * 4096, ub1 + i * 64,
                                                      uW2h + i * 4096, ub2 + i * 64, x);
  }

  hipMemsetAsync(pooled, 0, (size_t)(N_GRAPHS * HID + N_GRAPHS) * sizeof(float), stream);
  pool_kernel<<<(N_NODES / 64 + 1 + 3) / 4, 256, 0, stream>>>(x, batch, pooled, counts);
  gate_kernel<<<N_GRAPHS / 4, 256, 0, stream>>>(pooled, counts, mlip,
                                                gW1, gb1, gW2, gb2, gW3, gb3,
                                                (float*)d_out);
}

// Round 8
// 395.324 us; speedup vs baseline: 2.7372x; 1.0608x over previous
//
#include <hip/hip_runtime.h>
#include <hip/hip_fp16.h>
#include <math.h>

#define N_NODES   100000
#define N_EDGES   1250000
#define HID       64
#define N_RBF     32
#define N_GRAPHS  512
#define N_EXPERTS 8
#define N_LAYERS  3
#define CUTOFF    6.0f
#define GATE_IN   72
#define G1_DIM    64
#define G2_DIM    32
#define K_TAB     4096   // nearest-neighbor table cells (12-bit index)
#define N_BUCKET  391    // 256-node buckets
#define BUCKET_CAP 4608  // mean 3200, sigma 56.5 -> +25 sigma
#define CHUNK_A   2048   // 611 blocks -> 2.4/CU (R7: 153 blocks = 5% occupancy)

typedef short short8 __attribute__((ext_vector_type(8)));
typedef float float4v __attribute__((ext_vector_type(4)));

// e5m2 encode: fp16 bits, round-half-up in magnitude, keep high byte.
__device__ __forceinline__ unsigned enc8(float v) {
  unsigned short u = __half_as_ushort(__float2half(v));
  return (unsigned)((unsigned short)(u + 0x80u) >> 8);
}
__device__ __forceinline__ float dec8(unsigned b) {
  return __half2float(__ushort_as_half((unsigned short)(b << 8)));
}
// bf16 round-to-nearest-even
__device__ __forceinline__ unsigned short bf16(float f) {
  unsigned u = __float_as_uint(f);
  u += 0x7fffu + ((u >> 16) & 1u);
  return (unsigned short)(u >> 16);
}

// ---------------------------------------------------------------------------
// Filter table (fp32 endpoints): f_i(w) = silu(rbf(w)@fW1^T+fb1)@fW2^T+fb2
// ---------------------------------------------------------------------------
__global__ __launch_bounds__(256) void build_tab(
    const float* __restrict__ fW1, const float* __restrict__ fb1,
    const float* __restrict__ fW2, const float* __restrict__ fb2,
    float* __restrict__ tab) {
  __shared__ float W1s[64][33];
  __shared__ float W2s[64][65];
  __shared__ float rbfs[4][32];
  __shared__ float h1s[4][64];
  int t = threadIdx.x;
  int wv = t >> 6, lane = t & 63;
  int layer = blockIdx.x / 1025;
  int k = (blockIdx.x % 1025) * 4 + wv;

  for (int i = t; i < 64 * 32; i += 256) W1s[i >> 5][i & 31] = fW1[layer * 2048 + i];
  for (int i = t; i < 64 * 64; i += 256) W2s[i >> 6][i & 63] = fW2[layer * 4096 + i];

  float w = (CUTOFF / (float)K_TAB) * (float)k;
  const float delta = CUTOFF / (float)(N_RBF - 1);
  const float coeff = -0.5f / (delta * delta);
  __syncthreads();

  if (lane < N_RBF) {
    float d = w - delta * (float)lane;
    rbfs[wv][lane] = expf(coeff * d * d);
  }
  __syncthreads();

  float s = fb1[layer * HID + lane];
#pragma unroll
  for (int j = 0; j < N_RBF; j++) s += rbfs[wv][j] * W1s[lane][j];
  h1s[wv][lane] = s / (1.0f + expf(-s));
  __syncthreads();

  float f = fb2[layer * HID + lane];
#pragma unroll
  for (int c = 0; c < HID; c++) f += h1s[wv][c] * W2s[lane][c];
  if (k <= K_TAB) tab[(layer * (K_TAB + 1) + k) * HID + lane] = f;
}

// Nearest-value table: tab8[layer][k][lane] = e5m2( (f[k]+f[k+1])/2 )
__global__ __launch_bounds__(256) void pack_tab8(
    const float* __restrict__ tab, unsigned char* __restrict__ tab8) {
  int i = blockIdx.x * 256 + threadIdx.x;     // 3*4096*64
  if (i >= N_LAYERS * K_TAB * 64) return;
  int layer = i / (K_TAB * 64);
  int r = i - layer * (K_TAB * 64);
  const float* base = tab + layer * (K_TAB + 1) * 64;
  tab8[i] = (unsigned char)enc8(0.5f * (base[r] + base[r + 64]));
}

// Convert SchNet weights to bf16 (once per launch).
__global__ __launch_bounds__(256) void conv_w(
    const float* __restrict__ dW, const float* __restrict__ uW1,
    const float* __restrict__ uW2, unsigned short* __restrict__ dWh,
    unsigned short* __restrict__ uW1h, unsigned short* __restrict__ uW2h) {
  int i = blockIdx.x * 256 + threadIdx.x;
  if (i < N_LAYERS * 4096) {
    dWh[i]  = bf16(dW[i]);
    uW1h[i] = bf16(uW1[i]);
    uW2h[i] = bf16(uW2[i]);
  }
}

// ---------------------------------------------------------------------------
// Phase A: partition edges into 391 fixed-capacity buckets (256 nodes each).
// rec = (src << 12) | wq, wq = floor(ew * K_TAB/CUTOFF) (nearest-cell index).
// ---------------------------------------------------------------------------
__global__ __launch_bounds__(256) void partitionA(
    const int* __restrict__ src, const int* __restrict__ dst,
    const float* __restrict__ ew, int* __restrict__ gcnt,
    uint2* __restrict__ stage) {
  __shared__ int hist[N_BUCKET];
  __shared__ int base[N_BUCKET];
  int t = threadIdx.x;
  int e0 = blockIdx.x * CHUNK_A;
  int e1 = e0 + CHUNK_A; if (e1 > N_EDGES) e1 = N_EDGES;

  for (int i = t; i < N_BUCKET; i += 256) hist[i] = 0;
  __syncthreads();
  for (int e = e0 + t; e < e1; e += 256)
    atomicAdd(&hist[dst[e] >> 8], 1);
  __syncthreads();
  for (int i = t; i < N_BUCKET; i += 256) {
    int c = hist[i];
    base[i] = c ? atomicAdd(&gcnt[i], c) : 0;
    hist[i] = 0;
  }
  __syncthreads();
  for (int e = e0 + t; e < e1; e += 256) {
    int d = dst[e];
    int b = d >> 8;
    int r = base[b] + atomicAdd(&hist[b], 1);
    if (r < BUCKET_CAP) {
      float uq = ew[e] * ((float)K_TAB / CUTOFF);
      int wq = (int)uq;
      if (wq > K_TAB - 1) wq = K_TAB - 1;
      stage[(size_t)b * BUCKET_CAP + r] =
          make_uint2(((unsigned)src[e] << 12) | (unsigned)wq, (unsigned)d);
    }
  }
}

// Scan bucket counts -> bucket bases; also rowstart[N_NODES].
__global__ __launch_bounds__(512) void bscan_kernel(
    const int* __restrict__ gcnt, int* __restrict__ bbase,
    int* __restrict__ rowstart) {
  __shared__ int sh[512];
  int t = threadIdx.x;
  int v = 0;
  if (t < N_BUCKET) {
    v = gcnt[t];
    if (v > BUCKET_CAP) v = BUCKET_CAP;
  }
  sh[t] = v;
  __syncthreads();
  for (int off = 1; off < 512; off <<= 1) {
    int add = (t >= off) ? sh[t - off] : 0;
    __syncthreads();
    sh[t] += add;
    __syncthreads();
  }
  if (t < N_BUCKET) bbase[t] = sh[t] - v;
  if (t == N_BUCKET - 1) {
    bbase[N_BUCKET] = sh[t];
    rowstart[N_NODES] = sh[t];
  }
}

// ---------------------------------------------------------------------------
// Phase B: one 512-thread block per bucket; LDS counting sort -> CSR + rowstart.
// ---------------------------------------------------------------------------
__global__ __launch_bounds__(512) void sortB(
    const int* __restrict__ bbase, const uint2* __restrict__ stage,
    int* __restrict__ rowstart, unsigned* __restrict__ recs) {
  __shared__ int cnt[256];
  __shared__ int scn[256];
  __shared__ unsigned dest[BUCKET_CAP];
  int t = threadIdx.x;
  int b = blockIdx.x;
  int node0 = b << 8;
  int base = bbase[b];
  int total = bbase[b + 1] - base;
  const uint2* st = stage + (size_t)b * BUCKET_CAP;

  if (t < 256) cnt[t] = 0;
  __syncthreads();
  for (int k = t; k < total; k += 512) atomicAdd(&cnt[(int)st[k].y - node0], 1);
  __syncthreads();
  int v = 0;
  if (t < 256) { v = cnt[t]; scn[t] = v; }
  __syncthreads();
  for (int off = 1; off < 256; off <<= 1) {
    int add = (t < 256 && t >= off) ? scn[t - off] : 0;
    __syncthreads();
    if (t < 256) scn[t] += add;
    __syncthreads();
  }
  if (t < 256) {
    int excl = scn[t] - v;
    int n = node0 + t;
    if (n < N_NODES) rowstart[n] = base + excl;
    scn[t] = excl;
    cnt[t] = 0;
  }
  __syncthreads();
  for (int k = t; k < total; k += 512) {
    uint2 e = st[k];
    int ln = (int)e.y - node0;
    int r = atomicAdd(&cnt[ln], 1);
    dest[scn[ln] + r] = e.x;
  }
  __syncthreads();
  for (int k = t; k < total; k += 512) recs[base + k] = dest[k];
}

// ---------------------------------------------------------------------------
// dense0 (MFMA): y[n] = emb[z[n]] @ W^T + b -> e5m2 bytes (layer 0 only;
// emb is a 25.6 KB L1-resident table -> no x stream needed).
// ---------------------------------------------------------------------------
__global__ __launch_bounds__(256, 4) void dense0(
    const int* __restrict__ z, const float* __restrict__ emb,
    const unsigned short* __restrict__ Wh,
    const float* __restrict__ b, unsigned char* __restrict__ yb) {
  __shared__ __align__(16) unsigned char smem[18432];
  short* As = (short*)smem;            // [64][72] bf16
  short* Bs = As + 64 * 72;            // [64][72] bf16
  float* Es = (float*)smem;            // [64][68] epilogue (reuse)
  int t = threadIdx.x;
  int row0 = blockIdx.x * 64;

#pragma unroll
  for (int it = 0; it < 4; it++) {
    int i = it * 1024 + t * 4;
    int r = i >> 6, c = i & 63;
    int gr = row0 + r;
    float4 v = make_float4(0.f, 0.f, 0.f, 0.f);
    if (gr < N_NODES) {
      int zi = z[gr];
      v = *(const float4*)&emb[(size_t)zi * 64 + c];
    }
    short4 h;
    h.x = (short)bf16(v.x); h.y = (short)bf16(v.y);
    h.z = (short)bf16(v.z); h.w = (short)bf16(v.w);
    *(short4*)&As[r * 72 + c] = h;
  }
#pragma unroll
  for (int it = 0; it < 2; it++) {
    int i = it * 2048 + t * 8;
    int r = i >> 6, c = i & 63;
    *(uint4*)&Bs[r * 72 + c] = *(const uint4*)&Wh[i];
  }
  __syncthreads();

  int lane = t & 63, wv = t >> 6;
  int m = lane & 15, quad = lane >> 4;
  const short* arow = As + (wv * 16 + m) * 72 + quad * 8;
  short8 a0 = *(const short8*)arow;
  short8 a1 = *(const short8*)(arow + 32);
  float4v acc[4];
#pragma unroll
  for (int ct = 0; ct < 4; ct++) {
    const short* brow = Bs + (ct * 16 + m) * 72 + quad * 8;
    short8 bf0 = *(const short8*)brow;
    short8 bf1 = *(const short8*)(brow + 32);
    float bj = b[ct * 16 + m];
    float4v c = {bj, bj, bj, bj};
    c = __builtin_amdgcn_mfma_f32_16x16x32_bf16(a0, bf0, c, 0, 0, 0);
    c = __builtin_amdgcn_mfma_f32_16x16x32_bf16(a1, bf1, c, 0, 0, 0);
    acc[ct] = c;
  }
  __syncthreads();
#pragma unroll
  for (int ct = 0; ct < 4; ct++)
#pragma unroll
    for (int r = 0; r < 4; r++)
      Es[(wv * 16 + quad * 4 + r) * 68 + ct * 16 + m] = acc[ct][r];
  __syncthreads();
  {
    int row = t >> 2, c0 = (t & 3) * 16;
    int gr = row0 + row;
    if (gr < N_NODES) {
      unsigned w[4];
#pragma unroll
      for (int q = 0; q < 4; q++) {
        const float* p = &Es[row * 68 + c0 + 4 * q];
        w[q] = enc8(p[0]) | (enc8(p[1]) << 8) | (enc8(p[2]) << 16) | (enc8(p[3]) << 24);
      }
      *(uint4*)&yb[(size_t)gr * 64 + c0] = make_uint4(w[0], w[1], w[2], w[3]);
    }
  }
}

// ---------------------------------------------------------------------------
// update_dense (MFMA, fused): xnew = xold + silu(agg@W1^T+b1)@W2^T+b2;
// writes xnew to x; if dWn != null also emits y = xnew@dWn^T+dbn -> yb
// (next layer's dense, x-tile never leaves LDS). Layer 0: xold = emb[z].
// ---------------------------------------------------------------------------
__global__ __launch_bounds__(256, 4) void update_dense(
    const unsigned short* __restrict__ aggb,
    const unsigned short* __restrict__ W1h, const float* __restrict__ ub1,
    const unsigned short* __restrict__ W2h, const float* __restrict__ ub2,
    float* __restrict__ x,
    const int* __restrict__ z, const float* __restrict__ emb,
    const unsigned short* __restrict__ dWn, const float* __restrict__ dbn,
    unsigned char* __restrict__ yb) {
  __shared__ __align__(16) short A1[64 * 72];   // 9216 B
  __shared__ __align__(16) short B1[64 * 72];   // 9216 B
  __shared__ __align__(16) float E[64 * 68];    // 17408 B (x-tile fp32)
  int t = threadIdx.x;
  int row0 = blockIdx.x * 64;
  int lane = t & 63, wv = t >> 6;
  int m = lane & 15, quad = lane >> 4;

  // stage xold -> E (fp32)
#pragma unroll
  for (int it = 0; it < 4; it++) {
    int i = it * 1024 + t * 4;
    int r = i >> 6, c = i & 63;
    int gr = row0 + r;
    float4 v = make_float4(0.f, 0.f, 0.f, 0.f);
    if (gr < N_NODES) {
      if (z) {
        int zi = z[gr];
        v = *(const float4*)&emb[(size_t)zi * 64 + c];
      } else {
        v = *(const float4*)&x[(size_t)gr * 64 + c];
      }
    }
    *(float4*)&E[r * 68 + c] = v;
  }
  // stage agg (bf16) -> A1, W1 -> B1
#pragma unroll
  for (int it = 0; it < 2; it++) {
    int i = it * 2048 + t * 8;
    int r = i >> 6, c = i & 63;
    int gr = row0 + r;
    uint4 v = make_uint4(0u, 0u, 0u, 0u);
    if (gr < N_NODES) v = *(const uint4*)&aggb[(size_t)gr * 64 + c];
    *(uint4*)&A1[r * 72 + c] = v;
    *(uint4*)&B1[r * 72 + c] = *(const uint4*)&W1h[i];
  }
  __syncthreads();

  const short* arow = A1 + (wv * 16 + m) * 72 + quad * 8;
  float4v acc[4];
  {
    short8 a0 = *(const short8*)arow;
    short8 a1 = *(const short8*)(arow + 32);
#pragma unroll
    for (int ct = 0; ct < 4; ct++) {
      const short* brow = B1 + (ct * 16 + m) * 72 + quad * 8;
      short8 bf0 = *(const short8*)brow;
      short8 bf1 = *(const short8*)(brow + 32);
      float bj = ub1[ct * 16 + m];
      float4v c = {bj, bj, bj, bj};
      c = __builtin_amdgcn_mfma_f32_16x16x32_bf16(a0, bf0, c, 0, 0, 0);
      c = __builtin_amdgcn_mfma_f32_16x16x32_bf16(a1, bf1, c, 0, 0, 0);
      acc[ct] = c;
    }
  }
  __syncthreads();
  // h = silu -> A1, restage B1 = W2
#pragma unroll
  for (int ct = 0; ct < 4; ct++)
#pragma unroll
    for (int r = 0; r < 4; r++) {
      float s = acc[ct][r];
      float h = s / (1.0f + expf(-s));
      A1[(wv * 16 + quad * 4 + r) * 72 + ct * 16 + m] = (short)bf16(h);
    }
#pragma unroll
  for (int it = 0; it < 2; it++) {
    int i = it * 2048 + t * 8;
    int r = i >> 6, c = i & 63;
    *(uint4*)&B1[r * 72 + c] = *(const uint4*)&W2h[i];
  }
  __syncthreads();

  {
    short8 a0 = *(const short8*)arow;
    short8 a1 = *(const short8*)(arow + 32);
#pragma unroll
    for (int ct = 0; ct < 4; ct++) {
      const short* brow = B1 + (ct * 16 + m) * 72 + quad * 8;
      short8 bf0 = *(const short8*)brow;
      short8 bf1 = *(const short8*)(brow + 32);
      float bj = ub2[ct * 16 + m];
      float4v c = {bj, bj, bj, bj};
      c = __builtin_amdgcn_mfma_f32_16x16x32_bf16(a0, bf0, c, 0, 0, 0);
      c = __builtin_amdgcn_mfma_f32_16x16x32_bf16(a1, bf1, c, 0, 0, 0);
      acc[ct] = c;
    }
  }
  __syncthreads();   // phase-2 A1/B1 reads done; E staging long since done
  // E += delta (disjoint cells)
#pragma unroll
  for (int ct = 0; ct < 4; ct++)
#pragma unroll
    for (int r = 0; r < 4; r++)
      E[(wv * 16 + quad * 4 + r) * 68 + ct * 16 + m] += acc[ct][r];
  __syncthreads();
  // write xnew (coalesced)
  {
    int row = t >> 2, c0 = (t & 3) * 16;
    int gr = row0 + row;
    if (gr < N_NODES) {
      float* xp = x + (size_t)gr * 64 + c0;
#pragma unroll
      for (int q = 0; q < 4; q++)
        *(float4*)(xp + 4 * q) = *(const float4*)&E[row * 68 + c0 + 4 * q];
    }
  }
  if (!dWn) return;

  // fused next-layer dense: A1 = bf16(E), B1 = dWn
#pragma unroll
  for (int it = 0; it < 4; it++) {
    int i = it * 1024 + t * 4;
    int r = i >> 6, c = i & 63;
    float4 v = *(const float4*)&E[r * 68 + c];
    short4 h;
    h.x = (short)bf16(v.x); h.y = (short)bf16(v.y);
    h.z = (short)bf16(v.z); h.w = (short)bf16(v.w);
    *(short4*)&A1[r * 72 + c] = h;
  }
#pragma unroll
  for (int it = 0; it < 2; it++) {
    int i = it * 2048 + t * 8;
    int r = i >> 6, c = i & 63;
    *(uint4*)&B1[r * 72 + c] = *(const uint4*)&dWn[i];
  }
  __syncthreads();
  {
    short8 a0 = *(const short8*)arow;
    short8 a1 = *(const short8*)(arow + 32);
#pragma unroll
    for (int ct = 0; ct < 4; ct++) {
      const short* brow = B1 + (ct * 16 + m) * 72 + quad * 8;
      short8 bf0 = *(const short8*)brow;
      short8 bf1 = *(const short8*)(brow + 32);
      float bj = dbn[ct * 16 + m];
      float4v c = {bj, bj, bj, bj};
      c = __builtin_amdgcn_mfma_f32_16x16x32_bf16(a0, bf0, c, 0, 0, 0);
      c = __builtin_amdgcn_mfma_f32_16x16x32_bf16(a1, bf1, c, 0, 0, 0);
      acc[ct] = c;
    }
  }
  __syncthreads();   // E readers (A1 build) done before overwrite
#pragma unroll
  for (int ct = 0; ct < 4; ct++)
#pragma unroll
    for (int r = 0; r < 4; r++)
      E[(wv * 16 + quad * 4 + r) * 68 + ct * 16 + m] = acc[ct][r];
  __syncthreads();
  {
    int row = t >> 2, c0 = (t & 3) * 16;
    int gr = row0 + row;
    if (gr < N_NODES) {
      unsigned w[4];
#pragma unroll
      for (int q = 0; q < 4; q++) {
        const float* p = &E[row * 68 + c0 + 4 * q];
        w[q] = enc8(p[0]) | (enc8(p[1]) << 8) | (enc8(p[2]) << 16) | (enc8(p[3]) << 24);
      }
      *(uint4*)&yb[(size_t)gr * 64 + c0] = make_uint4(w[0], w[1], w[2], w[3]);
    }
  }
}

// ---------------------------------------------------------------------------
// CSR gather: scalarized records, nearest-value e5m2 table (1 byte), e5m2 y.
// ---------------------------------------------------------------------------
__global__ __launch_bounds__(256) void gather_kernel(
    const int* __restrict__ rowstart, const unsigned* __restrict__ recs,
    const unsigned char* __restrict__ tab8,
    const unsigned char* __restrict__ yb,
    unsigned short* __restrict__ aggb) {
  int d = blockIdx.x * 4 + (threadIdx.x >> 6);
  int lane = threadIdx.x & 63;
  int b0 = __builtin_amdgcn_readfirstlane(rowstart[d]);
  int b1 = __builtin_amdgcn_readfirstlane(rowstart[d + 1]);
  float acc = 0.0f;
  int j = b0;
  for (; j + 4 <= b1; j += 4) {
    unsigned u0 = recs[j];
    unsigned u1 = recs[j + 1];
    unsigned u2 = recs[j + 2];
    unsigned u3 = recs[j + 3];
    unsigned y0 = yb[((u0 >> 12) << 6) + lane];
    unsigned y1 = yb[((u1 >> 12) << 6) + lane];
    unsigned y2 = yb[((u2 >> 12) << 6) + lane];
    unsigned y3 = yb[((u3 >> 12) << 6) + lane];
    unsigned f0 = tab8[((u0 & 4095u) << 6) + lane];
    unsigned f1 = tab8[((u1 & 4095u) << 6) + lane];
    unsigned f2 = tab8[((u2 & 4095u) << 6) + lane];
    unsigned f3 = tab8[((u3 & 4095u) << 6) + lane];
    acc += dec8(y0) * dec8(f0);
    acc += dec8(y1) * dec8(f1);
    acc += dec8(y2) * dec8(f2);
    acc += dec8(y3) * dec8(f3);
  }
  for (; j < b1; j++) {
    unsigned u = recs[j];
    unsigned yv = yb[((u >> 12) << 6) + lane];
    unsigned fv = tab8[((u & 4095u) << 6) + lane];
    acc += dec8(yv) * dec8(fv);
  }
  aggb[(size_t)d * 64 + lane] = bf16(acc);
}

// ---------------------------------------------------------------------------
__global__ __launch_bounds__(256) void pool_kernel(
    const float* __restrict__ x, const int* __restrict__ batch,
    float* __restrict__ pooled, float* __restrict__ counts) {
  int wid = (blockIdx.x * 256 + threadIdx.x) >> 6;
  int lane = threadIdx.x & 63;
  int n0 = wid * 64;
  if (n0 >= N_NODES) return;
  int n1 = n0 + 64; if (n1 > N_NODES) n1 = N_NODES;
  int curg = batch[n0];
  float acc = 0.0f, cnt = 0.0f;
  for (int n = n0; n < n1; n++) {
    int g = batch[n];
    if (g != curg) {
      unsafeAtomicAdd(&pooled[curg * 64 + lane], acc);
      if (lane == 0) unsafeAtomicAdd(&counts[curg], cnt);
      curg = g; acc = 0.0f; cnt = 0.0f;
    }
    acc += x[n * 64 + lane];
    cnt += 1.0f;
  }
  unsafeAtomicAdd(&pooled[curg * 64 + lane], acc);
  if (lane == 0) unsafeAtomicAdd(&counts[curg], cnt);
}

// ---------------------------------------------------------------------------
__global__ __launch_bounds__(256) void gate_kernel(
    const float* __restrict__ pooled, const float* __restrict__ counts,
    const float* __restrict__ mlip,
    const float* __restrict__ gW1, const float* __restrict__ gb1,
    const float* __restrict__ gW2, const float* __restrict__ gb2,
    const float* __restrict__ gW3, const float* __restrict__ gb3,
    float* __restrict__ out) {
  __shared__ float ins[4][GATE_IN];
  __shared__ float h1s[4][G1_DIM];
  __shared__ float h2s[4][G2_DIM];
  __shared__ float lg[4][N_EXPERTS];
  int wv = threadIdx.x >> 6, lane = threadIdx.x & 63;
  int g = blockIdx.x * 4 + wv;

  float cnt = counts[g];
  if (cnt < 1.0f) cnt = 1.0f;
  ins[wv][lane] = pooled[g * 64 + lane] / cnt;
  if (lane < N_EXPERTS) ins[wv][64 + lane] = mlip[g * N_EXPERTS + lane];
  __syncthreads();

  {
    float s = gb1[lane];
    for (int c = 0; c < GATE_IN; c++) s += ins[wv][c] * gW1[lane * GATE_IN + c];
    h1s[wv][lane] = fmaxf(s, 0.0f);
  }
  __syncthreads();
  if (lane < G2_DIM) {
    float s = gb2[lane];
    for (int c = 0; c < G1_DIM; c++) s += h1s[wv][c] * gW2[lane * G1_DIM + c];
    h2s[wv][lane] = fmaxf(s, 0.0f);
  }
  __syncthreads();
  if (lane < N_EXPERTS) {
    float s = gb3[lane];
    for (int c = 0; c < G2_DIM; c++) s += h2s[wv][c] * gW3[lane * G2_DIM + c];
    lg[wv][lane] = s;
  }
  __syncthreads();
  if (lane < N_EXPERTS) {
    float m = -1e30f;
    for (int j = 0; j < N_EXPERTS; j++) m = fmaxf(m, lg[wv][j]);
    float den = 0.0f;
    for (int j = 0; j < N_EXPERTS; j++) den += expf(lg[wv][j] - m);
    float wgt = expf(lg[wv][lane] - m) / den;
    out[g * 8 + lane] = lg[wv][lane];
    out[N_GRAPHS * 8 + g * 8 + lane] = wgt;
    if (lane == 0) {
      float p = 0.0f;
      for (int j = 0; j < N_EXPERTS; j++)
        p += mlip[g * 8 + j] * expf(lg[wv][j] - m) / den;
      out[N_GRAPHS * 16 + g] = p;
    }
  }
}

// ---------------------------------------------------------------------------
extern "C" void kernel_launch(void* const* d_in, const int* in_sizes, int n_in,
                              void* d_out, int out_size, void* d_ws, size_t ws_size,
                              hipStream_t stream) {
  const int*   z     = (const int*)  d_in[0];
  const int*   ei    = (const int*)  d_in[1];
  const float* ew    = (const float*)d_in[2];
  const int*   batch = (const int*)  d_in[3];
  const float* mlip  = (const float*)d_in[4];
  const float* emb   = (const float*)d_in[5];
  const float* fW1   = (const float*)d_in[6];
  const float* fb1   = (const float*)d_in[7];
  const float* fW2   = (const float*)d_in[8];
  const float* fb2   = (const float*)d_in[9];
  const float* dW    = (const float*)d_in[10];
  const float* db    = (const float*)d_in[11];
  const float* uW1   = (const float*)d_in[12];
  const float* ub1   = (const float*)d_in[13];
  const float* uW2   = (const float*)d_in[14];
  const float* ub2   = (const float*)d_in[15];
  const float* gW1   = (const float*)d_in[16];
  const float* gb1   = (const float*)d_in[17];
  const float* gW2   = (const float*)d_in[18];
  const float* gb2   = (const float*)d_in[19];
  const float* gW3   = (const float*)d_in[20];
  const float* gb3   = (const float*)d_in[21];

  const int* src = ei;
  const int* dst = ei + N_EDGES;

  float* ws = (float*)d_ws;
  float*          x        = ws;                               // 6,400,000 f
  unsigned char*  yb       = (unsigned char*)(ws + 6400000);   // 6.4 MB
  unsigned short* aggb     = (unsigned short*)(ws + 8000000);  // 12.8 MB
  float*          tab      = ws + 11200000;                    // 786,624 f
  unsigned char*  tab8     = (unsigned char*)(ws + 11986624);  // 786,432 B
  float*          pooled   = ws + 12183232;                    // 32,768
  float*          counts   = ws + 12216000;                    // 512
  int*            rowstart = (int*)(ws + 12216512);            // 100,001
  unsigned*       recs     = (unsigned*)(ws + 12316513);       // 1,250,000
  int*            gcnt     = (int*)(ws + 13566513);            // 391
  int*            bbase    = (int*)(ws + 13566904);            // 392
  uint2*          stage    = (uint2*)(ws + 13567296);          // 391*4608*8 B
  unsigned short* dWh      = (unsigned short*)(ws + 17171008); // 3*4096 bf16
  unsigned short* uW1h     = dWh + N_LAYERS * 4096;
  unsigned short* uW2h     = uW1h + N_LAYERS * 4096;           // end ~68.8 MB

  // --- CSR build (once per launch) ---
  hipMemsetAsync(gcnt, 0, N_BUCKET * sizeof(int), stream);
  partitionA<<<(N_EDGES + CHUNK_A - 1) / CHUNK_A, 256, 0, stream>>>(
      src, dst, ew, gcnt, stage);
  bscan_kernel<<<1, 512, 0, stream>>>(gcnt, bbase, rowstart);
  sortB<<<N_BUCKET, 512, 0, stream>>>(bbase, stage, rowstart, recs);

  build_tab<<<N_LAYERS * 1025, 256, 0, stream>>>(fW1, fb1, fW2, fb2, tab);
  pack_tab8<<<(N_LAYERS * K_TAB * 64) / 256, 256, 0, stream>>>(tab, tab8);
  conv_w<<<(N_LAYERS * 4096 + 255) / 256, 256, 0, stream>>>(dW, uW1, uW2, dWh, uW1h, uW2h);

  const int NBLK = (N_NODES + 63) / 64;
  dense0<<<NBLK, 256, 0, stream>>>(z, emb, dWh, db, yb);

  // layer 0: gather, then fused update(L0)+dense(L1); xold = emb[z]
  gather_kernel<<<N_NODES / 4, 256, 0, stream>>>(rowstart, recs, tab8, yb, aggb);
  update_dense<<<NBLK, 256, 0, stream>>>(aggb, uW1h, ub1, uW2h, ub2, x,
                                         z, emb, dWh + 4096, db + 64, yb);
  // layer 1: gather, fused update(L1)+dense(L2)
  gather_kernel<<<N_NODES / 4, 256, 0, stream>>>(rowstart, recs, tab8 + K_TAB * 64, yb, aggb);
  update_dense<<<NBLK, 256, 0, stream>>>(aggb, uW1h + 4096, ub1 + 64, uW2h + 4096, ub2 + 64, x,
                                         nullptr, nullptr, dWh + 8192, db + 128, yb);
  // layer 2: gather, final update (no fused dense)
  gather_kernel<<<N_NODES / 4, 256, 0, stream>>>(rowstart, recs, tab8 + 2 * K_TAB * 64, yb, aggb);
  update_dense<<<NBLK, 256, 0, stream>>>(aggb, uW1h + 8192, ub1 + 128, uW2h + 8192, ub2 + 128, x,
                                         nullptr, nullptr, nullptr, nullptr, nullptr);

  hipMemsetAsync(pooled, 0, (size_t)(N_GRAPHS * HID + N_GRAPHS) * sizeof(float), stream);
  pool_kernel<<<(N_NODES / 64 + 1 + 3) / 4, 256, 0, stream>>>(x, batch, pooled, counts);
  gate_kernel<<<N_GRAPHS / 4, 256, 0, stream>>>(pooled, counts, mlip,
                                                gW1, gb1, gW2, gb2, gW3, gb3,
                                                (float*)d_out);
}